// Round 9
// baseline (1889.021 us; speedup 1.0000x reference)
//
#include <hip/hip_runtime.h>
#include <math.h>

#define N_ENTS 50000
#define N_RELS 500
#define N_ALL  50500
#define EMB    256
#define NEDGE  400000
#define BATCH  512
#define BN_EPS 1e-5f

typedef unsigned short u16;
typedef unsigned int   u32;
typedef __attribute__((ext_vector_type(8))) short s16x8;  // 8 bf16 (4 VGPRs)
typedef __attribute__((ext_vector_type(4))) float f32x4;  // MFMA acc

// LDS row stride in u16 for 32-wide K tiles: 40 shorts = 80 B, 16B-aligned
// chunks, 20-bank-quad stride => <=2-way (free) conflicts on fragment reads.
#define LSTR 40

// ---------------------------------------------------------------------------
// bf16 split helpers (RNE). x = hi + lo with |x-hi-lo| ~ 2^-17|x|.
// ---------------------------------------------------------------------------
__device__ __forceinline__ u16 f2b(float x) {
    u32 u = __float_as_uint(x);
    return (u16)((u + 0x7fffu + ((u >> 16) & 1u)) >> 16);
}
__device__ __forceinline__ float b2f(u16 h) {
    return __uint_as_float((u32)h << 16);
}

// Split fp32 array into bf16 hi/lo arrays. n4 = count of float4 groups.
__global__ __launch_bounds__(256) void split_kernel(
    const float* __restrict__ x, u16* __restrict__ hi, u16* __restrict__ lo,
    long n4) {
    long i = (long)blockIdx.x * 256 + threadIdx.x;
    if (i >= n4) return;
    float4 v = ((const float4*)x)[i];
    u16 h0 = f2b(v.x), h1 = f2b(v.y), h2 = f2b(v.z), h3 = f2b(v.w);
    u16 l0 = f2b(v.x - b2f(h0)), l1 = f2b(v.y - b2f(h1));
    u16 l2 = f2b(v.z - b2f(h2)), l3 = f2b(v.w - b2f(h3));
    uint2 hp, lp;
    hp.x = (u32)h0 | ((u32)h1 << 16); hp.y = (u32)h2 | ((u32)h3 << 16);
    lp.x = (u32)l0 | ((u32)l1 << 16); lp.y = (u32)l2 | ((u32)l3 << 16);
    ((uint2*)hi)[i] = hp;
    ((uint2*)lo)[i] = lp;
}

// ---------------------------------------------------------------------------
// Build TRANSPOSED hamilton HT[n][k] (256 rows, K=4P cols), pre-split bf16.
// ---------------------------------------------------------------------------
__global__ __launch_bounds__(256) void build_ht_kernel(
    const float* __restrict__ W, u16* __restrict__ Hhi, u16* __restrict__ Hlo,
    int P) {
    int K4 = 4 * P;
    int idx = blockIdx.x * 256 + threadIdx.x;
    int total = 256 * K4;
    if (idx >= total) return;
    int n = idx / K4, k = idx - n * K4;
    int a = k / P, p = k - a * P;
    int c = n >> 6, s = n & 63;
    const int  comp[4][4] = {{0,1,2,3},{1,0,3,2},{2,3,0,1},{3,2,1,0}};
    const float sgn[4][4] = {{1.f,1.f,1.f,1.f},
                             {-1.f,1.f,1.f,-1.f},
                             {-1.f,-1.f,1.f,1.f},
                             {-1.f,1.f,-1.f,1.f}};
    float v = sgn[a][c] * W[p * 256 + comp[a][c] * 64 + s];
    u16 h = f2b(v);
    Hhi[idx] = h;
    Hlo[idx] = f2b(v - b2f(h));
}

// ---------------------------------------------------------------------------
// MFMA GEMM core (BT form): C[m][n] = sum_k A[m][k]*Bt[n][k].
// Block 256 thr = 4 waves as 2Mx2N, tile 128x256, wave tile 64x128.
// K-step 32, mfma_f32_16x16x32_bf16, split-bf16 3-term.
// ---------------------------------------------------------------------------
template <int ROWS>
__device__ __forceinline__ void stage_rows(
    const u16* __restrict__ Shi, const u16* __restrict__ Slo,
    long row0, int rows_left, int K, int k0,
    u16* __restrict__ Lh, u16* __restrict__ Ll, int tid) {
#pragma unroll
    for (int p = 0; p < ROWS / 64; p++) {
        int idx = tid + p * 256;
        int r = idx >> 2, c = idx & 3;
        uint4 vh = make_uint4(0, 0, 0, 0), vl = make_uint4(0, 0, 0, 0);
        if (r < rows_left) {
            long base = (row0 + r) * (long)K + k0 + c * 8;
            vh = *(const uint4*)&Shi[base];
            vl = *(const uint4*)&Slo[base];
        }
        *(uint4*)&Lh[r * LSTR + c * 8] = vh;
        *(uint4*)&Ll[r * LSTR + c * 8] = vl;
    }
}

// Stage 128 rows x 32 cols of an fp32 matrix, splitting to bf16 hi/lo in
// LDS on the fly (for fp32 A-operands).
__device__ __forceinline__ void stage_f32_split(
    const float* __restrict__ S, long row0, int rows_left, int K, int k0,
    u16* __restrict__ Lh, u16* __restrict__ Ll, int tid) {
#pragma unroll
    for (int p = 0; p < 4; p++) {
        int idx = tid + p * 256;
        int r = idx >> 3, c4 = idx & 7;
        float4 v = make_float4(0.f, 0.f, 0.f, 0.f);
        if (r < rows_left)
            v = *(const float4*)&S[(row0 + r) * (long)K + k0 + c4 * 4];
        u16 h0 = f2b(v.x), h1 = f2b(v.y), h2 = f2b(v.z), h3 = f2b(v.w);
        u16 l0 = f2b(v.x - b2f(h0)), l1 = f2b(v.y - b2f(h1));
        u16 l2 = f2b(v.z - b2f(h2)), l3 = f2b(v.w - b2f(h3));
        uint2 hp, lp;
        hp.x = (u32)h0 | ((u32)h1 << 16); hp.y = (u32)h2 | ((u32)h3 << 16);
        lp.x = (u32)l0 | ((u32)l1 << 16); lp.y = (u32)l2 | ((u32)l3 << 16);
        *(uint2*)&Lh[r * LSTR + c4 * 4] = hp;
        *(uint2*)&Ll[r * LSTR + c4 * 4] = lp;
    }
}

__device__ __forceinline__ void mfma_tile256(
    const u16* __restrict__ Ah, const u16* __restrict__ Al,
    const u16* __restrict__ Bh, const u16* __restrict__ Bl,
    int wm, int wn, int lane, f32x4 acc[4][8]) {
    int lr = lane & 15, kg = lane >> 4;
    s16x8 ah[4], al[4];
#pragma unroll
    for (int fm = 0; fm < 4; fm++) {
        int off = (wm + fm * 16 + lr) * LSTR + kg * 8;
        ah[fm] = *(const s16x8*)&Ah[off];
        al[fm] = *(const s16x8*)&Al[off];
    }
#pragma unroll
    for (int fn = 0; fn < 8; fn++) {
        int off = (wn + fn * 16 + lr) * LSTR + kg * 8;
        s16x8 bh = *(const s16x8*)&Bh[off];
        s16x8 bl = *(const s16x8*)&Bl[off];
#pragma unroll
        for (int fm = 0; fm < 4; fm++) {
            acc[fm][fn] = __builtin_amdgcn_mfma_f32_16x16x32_bf16(
                ah[fm], bh, acc[fm][fn], 0, 0, 0);
            acc[fm][fn] = __builtin_amdgcn_mfma_f32_16x16x32_bf16(
                ah[fm], bl, acc[fm][fn], 0, 0, 0);
            acc[fm][fn] = __builtin_amdgcn_mfma_f32_16x16x32_bf16(
                al[fm], bh, acc[fm][fn], 0, 0, 0);
        }
    }
}

// Agg GEMM: agg[M,256] = G[M,256] @ HT^T. A = G fp32 (gather result),
// split in staging; Bt = HT split (256x256). fp32 output.
// ((A@X)@H form: support buffer round-trip eliminated.)
__global__ __launch_bounds__(256, 2) void mfma_agg_kernel(
    const float* __restrict__ G,
    const u16* __restrict__ Bhi, const u16* __restrict__ Blo,
    float* __restrict__ C, int M) {
    __shared__ u16 Ah[128 * LSTR], Al[128 * LSTR];
    __shared__ u16 Bh[256 * LSTR], Bl[256 * LSTR];
    int tid = threadIdx.x, lane = tid & 63, wid = tid >> 6;
    int wm = (wid >> 1) * 64, wn = (wid & 1) * 128;
    long bm0 = (long)blockIdx.y * 128;   // gridDim.x == 1 (N=256)
    int rA = (int)(((long)M - bm0 < 128) ? (long)M - bm0 : 128);
    f32x4 acc[4][8] = {};
    for (int k0 = 0; k0 < 256; k0 += 32) {
        if (k0) __syncthreads();
        stage_f32_split(G, bm0, rA, 256, k0, Ah, Al, tid);
        stage_rows<256>(Bhi, Blo, 0, 256, 256, k0, Bh, Bl, tid);
        __syncthreads();
        mfma_tile256(Ah, Al, Bh, Bl, wm, wn, lane, acc);
    }
    int lr = lane & 15, lq = lane >> 4;
#pragma unroll
    for (int fm = 0; fm < 4; fm++) {
#pragma unroll
        for (int r = 0; r < 4; r++) {
            long row = bm0 + wm + fm * 16 + lq * 4 + r;
            if (row < M) {
#pragma unroll
                for (int fn = 0; fn < 8; fn++) {
                    long col = wn + fn * 16 + lr;
                    C[row * 256 + col] = acc[fm][fn][r];
                }
            }
        }
    }
}

// Score GEMM: A=hrn split (512x256), Bt=X split (50000x256), sigmoid out.
__global__ __launch_bounds__(256, 2) void mfma_score_kernel(
    const u16* __restrict__ Ahi, const u16* __restrict__ Alo,
    const u16* __restrict__ Bhi, const u16* __restrict__ Blo,
    float* __restrict__ out) {
    __shared__ u16 Ah[128 * LSTR], Al[128 * LSTR];
    __shared__ u16 Bh[256 * LSTR], Bl[256 * LSTR];
    int tid = threadIdx.x, lane = tid & 63, wid = tid >> 6;
    int wm = (wid >> 1) * 64, wn = (wid & 1) * 128;
    long bm0 = (long)blockIdx.y * 128, bn0 = (long)blockIdx.x * 256;
    int rB = (int)(((long)N_ENTS - bn0 < 256) ? (long)N_ENTS - bn0 : 256);
    f32x4 acc[4][8] = {};
    for (int k0 = 0; k0 < 256; k0 += 32) {
        if (k0) __syncthreads();
        stage_rows<128>(Ahi, Alo, bm0, 128, 256, k0, Ah, Al, tid);
        stage_rows<256>(Bhi, Blo, bn0, rB, 256, k0, Bh, Bl, tid);
        __syncthreads();
        mfma_tile256(Ah, Al, Bh, Bl, wm, wn, lane, acc);
    }
    int lr = lane & 15, lq = lane >> 4;
#pragma unroll
    for (int fm = 0; fm < 4; fm++) {
#pragma unroll
        for (int r = 0; r < 4; r++) {
            long row = bm0 + wm + fm * 16 + lq * 4 + r;  // < 512 always
#pragma unroll
            for (int fn = 0; fn < 8; fn++) {
                long col = bn0 + wn + fn * 16 + lr;
                if (col < N_ENTS) {
                    float v = acc[fm][fn][r];
                    out[row * N_ENTS + col] = 1.f / (1.f + __expf(-v));
                }
            }
        }
    }
}

// Lin GEMM: Xcat[50000,512] @ H512. A-side converts fp32 interleave
// (Xef/Xrf) to split bf16 in-staging; Bt = HT512 split (256x512).
// Epilogue writes ONLY the bf16 hi/lo split.
__device__ __forceinline__ float4 lin_a_load(const float* __restrict__ Xef,
                                             const float* __restrict__ Xrf,
                                             int gm, int kk, int M) {
    int chunk = kk >> 6, s = kk & 63;
    const float* src = (chunk & 1) ? Xrf : Xef;
    float4 v = make_float4(0.f, 0.f, 0.f, 0.f);
    if (gm < M) v = *(const float4*)&src[(long)gm * 256 + (chunk >> 1) * 64 + s];
    return v;
}

__global__ __launch_bounds__(256, 2) void mfma_lin_kernel(
    const float* __restrict__ Xef, const float* __restrict__ Xrf,
    const u16* __restrict__ Bhi, const u16* __restrict__ Blo,
    u16* __restrict__ Chi, u16* __restrict__ Clo, int M) {
    __shared__ u16 Ah[128 * LSTR], Al[128 * LSTR];
    __shared__ u16 Bh[256 * LSTR], Bl[256 * LSTR];
    int tid = threadIdx.x, lane = tid & 63, wid = tid >> 6;
    int wm = (wid >> 1) * 64, wn = (wid & 1) * 128;
    int bm0 = blockIdx.y * 128;   // gridDim.x == 1 (N=256)
    f32x4 acc[4][8] = {};
    for (int k0 = 0; k0 < 512; k0 += 32) {
        if (k0) __syncthreads();
#pragma unroll
        for (int p = 0; p < 4; p++) {
            int idx = tid + p * 256;
            int r = idx >> 3, c4 = idx & 7;
            float4 v = lin_a_load(Xef, Xrf, bm0 + r, k0 + c4 * 4, M);
            u16 h0 = f2b(v.x), h1 = f2b(v.y), h2 = f2b(v.z), h3 = f2b(v.w);
            u16 l0 = f2b(v.x - b2f(h0)), l1 = f2b(v.y - b2f(h1));
            u16 l2 = f2b(v.z - b2f(h2)), l3 = f2b(v.w - b2f(h3));
            uint2 hp, lp;
            hp.x = (u32)h0 | ((u32)h1 << 16); hp.y = (u32)h2 | ((u32)h3 << 16);
            lp.x = (u32)l0 | ((u32)l1 << 16); lp.y = (u32)l2 | ((u32)l3 << 16);
            *(uint2*)&Ah[r * LSTR + c4 * 4] = hp;
            *(uint2*)&Al[r * LSTR + c4 * 4] = lp;
        }
        stage_rows<256>(Bhi, Blo, 0, 256, 512, k0, Bh, Bl, tid);
        __syncthreads();
        mfma_tile256(Ah, Al, Bh, Bl, wm, wn, lane, acc);
    }
    int lr = lane & 15, lq = lane >> 4;
#pragma unroll
    for (int fm = 0; fm < 4; fm++) {
#pragma unroll
        for (int r = 0; r < 4; r++) {
            long row = (long)bm0 + wm + fm * 16 + lq * 4 + r;
            if (row < M) {
#pragma unroll
                for (int fn = 0; fn < 8; fn++) {
                    long col = wn + fn * 16 + lr;
                    float v = acc[fm][fn][r];
                    u16 h = f2b(v);
                    Chi[row * 256 + col] = h;
                    Clo[row * 256 + col] = f2b(v - b2f(h));
                }
            }
        }
    }
}

// ---------------------------------------------------------------------------
// CSR build: histogram, single-block exclusive scan, ticket scatter.
// ---------------------------------------------------------------------------
__global__ __launch_bounds__(256) void hist_kernel(
    const int* __restrict__ rows, int* __restrict__ cnt, int n_edges) {
    int e = blockIdx.x * 256 + threadIdx.x;
    if (e < n_edges) atomicAdd(&cnt[rows[e]], 1);
}

__global__ __launch_bounds__(1024) void exscan_kernel(
    const int* __restrict__ cnt, int n, int* __restrict__ off) {
    __shared__ int part[1024];
    int t = threadIdx.x;
    int chunk = (n + 1023) / 1024;
    int lo = t * chunk;
    int hi = lo + chunk; if (hi > n) hi = n;
    int s = 0;
    for (int i = lo; i < hi; i++) s += cnt[i];
    part[t] = s;
    __syncthreads();
    for (int d = 1; d < 1024; d <<= 1) {
        int v = (t >= d) ? part[t - d] : 0;
        __syncthreads();
        part[t] += v;
        __syncthreads();
    }
    int base = (t == 0) ? 0 : part[t - 1];
    for (int i = lo; i < hi; i++) {
        off[i] = base;
        base += cnt[i];
    }
    if (hi >= n) off[n] = base;
}

__global__ __launch_bounds__(256) void scatter_kernel(
    const int* __restrict__ rows, const int* __restrict__ cols,
    const float* __restrict__ vals, int* __restrict__ cursor,
    int2* __restrict__ pack, int n_edges) {
    int e = blockIdx.x * 256 + threadIdx.x;
    if (e >= n_edges) return;
    int r = rows[e];
    int p = atomicAdd(&cursor[r], 1);
    pack[p] = make_int2(cols[e], __float_as_int(vals[e]));
}

// ---------------------------------------------------------------------------
// CSR gather-aggregate over the XR bf16 split ((A@X) form):
// G[row,:] = sum_e vals[e] * (xhi[cols[e],:]+xlo[cols[e],:]).
// One 64-lane wave per row; lane owns 4 cols. Unrolled x4: gathers are
// mutually independent -> 8 outstanding loads per lane (MLP).
// ---------------------------------------------------------------------------
__global__ __launch_bounds__(256) void csr_gather_kernel(
    const u16* __restrict__ xhi, const u16* __restrict__ xlo,
    const int* __restrict__ off, const int2* __restrict__ pack,
    float* __restrict__ G, int n_rows) {
    int gid = blockIdx.x * 256 + threadIdx.x;
    int row = gid >> 6;
    int lane = gid & 63;
    if (row >= n_rows) return;
    int beg = off[row], end = off[row + 1];
    float4 acc = {0.f, 0.f, 0.f, 0.f};
    int e = beg;
    for (; e + 4 <= end; e += 4) {
        int2 cv0 = pack[e], cv1 = pack[e + 1], cv2 = pack[e + 2], cv3 = pack[e + 3];
        long b0 = (long)cv0.x * 256 + lane * 4;
        long b1 = (long)cv1.x * 256 + lane * 4;
        long b2 = (long)cv2.x * 256 + lane * 4;
        long b3 = (long)cv3.x * 256 + lane * 4;
        uint2 h0 = *(const uint2*)(xhi + b0), l0 = *(const uint2*)(xlo + b0);
        uint2 h1 = *(const uint2*)(xhi + b1), l1 = *(const uint2*)(xlo + b1);
        uint2 h2 = *(const uint2*)(xhi + b2), l2 = *(const uint2*)(xlo + b2);
        uint2 h3 = *(const uint2*)(xhi + b3), l3 = *(const uint2*)(xlo + b3);
        float v0 = __int_as_float(cv0.y), v1 = __int_as_float(cv1.y);
        float v2 = __int_as_float(cv2.y), v3 = __int_as_float(cv3.y);
        acc.x = fmaf(v0, b2f((u16)(h0.x & 0xffff)) + b2f((u16)(l0.x & 0xffff)), acc.x);
        acc.y = fmaf(v0, b2f((u16)(h0.x >> 16))    + b2f((u16)(l0.x >> 16)),    acc.y);
        acc.z = fmaf(v0, b2f((u16)(h0.y & 0xffff)) + b2f((u16)(l0.y & 0xffff)), acc.z);
        acc.w = fmaf(v0, b2f((u16)(h0.y >> 16))    + b2f((u16)(l0.y >> 16)),    acc.w);
        acc.x = fmaf(v1, b2f((u16)(h1.x & 0xffff)) + b2f((u16)(l1.x & 0xffff)), acc.x);
        acc.y = fmaf(v1, b2f((u16)(h1.x >> 16))    + b2f((u16)(l1.x >> 16)),    acc.y);
        acc.z = fmaf(v1, b2f((u16)(h1.y & 0xffff)) + b2f((u16)(l1.y & 0xffff)), acc.z);
        acc.w = fmaf(v1, b2f((u16)(h1.y >> 16))    + b2f((u16)(l1.y >> 16)),    acc.w);
        acc.x = fmaf(v2, b2f((u16)(h2.x & 0xffff)) + b2f((u16)(l2.x & 0xffff)), acc.x);
        acc.y = fmaf(v2, b2f((u16)(h2.x >> 16))    + b2f((u16)(l2.x >> 16)),    acc.y);
        acc.z = fmaf(v2, b2f((u16)(h2.y & 0xffff)) + b2f((u16)(l2.y & 0xffff)), acc.z);
        acc.w = fmaf(v2, b2f((u16)(h2.y >> 16))    + b2f((u16)(l2.y >> 16)),    acc.w);
        acc.x = fmaf(v3, b2f((u16)(h3.x & 0xffff)) + b2f((u16)(l3.x & 0xffff)), acc.x);
        acc.y = fmaf(v3, b2f((u16)(h3.x >> 16))    + b2f((u16)(l3.x >> 16)),    acc.y);
        acc.z = fmaf(v3, b2f((u16)(h3.y & 0xffff)) + b2f((u16)(l3.y & 0xffff)), acc.z);
        acc.w = fmaf(v3, b2f((u16)(h3.y >> 16))    + b2f((u16)(l3.y >> 16)),    acc.w);
    }
    for (; e < end; e++) {
        int2 cv = pack[e];
        float v = __int_as_float(cv.y);
        long b = (long)cv.x * 256 + lane * 4;
        uint2 hv = *(const uint2*)(xhi + b), lv = *(const uint2*)(xlo + b);
        acc.x = fmaf(v, b2f((u16)(hv.x & 0xffff)) + b2f((u16)(lv.x & 0xffff)), acc.x);
        acc.y = fmaf(v, b2f((u16)(hv.x >> 16))    + b2f((u16)(lv.x >> 16)),    acc.y);
        acc.z = fmaf(v, b2f((u16)(hv.y & 0xffff)) + b2f((u16)(lv.y & 0xffff)), acc.z);
        acc.w = fmaf(v, b2f((u16)(hv.y >> 16))    + b2f((u16)(lv.y >> 16)),    acc.w);
    }
    *(float4*)(G + (long)row * 256 + lane * 4) = acc;
}

// ---------------------------------------------------------------------------
// Column stats + BN apply (+tanh fp32 variant; split-output variant for hrn)
// ---------------------------------------------------------------------------
__global__ __launch_bounds__(256) void bn_stats_kernel(
    const float* __restrict__ x, int n, float* __restrict__ stats) {
    int col = threadIdx.x;
    int r0 = blockIdx.x * 256;
    int r1 = r0 + 256;
    if (r1 > n) r1 = n;
    float s = 0.f, sq = 0.f;
    for (int r = r0; r < r1; r++) {
        float v = x[(long)r * 256 + col];
        s += v;
        sq += v * v;
    }
    atomicAdd(&stats[col], s);
    atomicAdd(&stats[256 + col], sq);
}

template <bool TANH>
__global__ __launch_bounds__(256) void bn_apply_kernel(
    const float* __restrict__ x, float* __restrict__ y, int n,
    const float* __restrict__ gamma, const float* __restrict__ beta,
    const float* __restrict__ stats) {
    long total = (long)n * 256;
    float inv_n = 1.f / (float)n;
    for (long idx = (long)blockIdx.x * 256 + threadIdx.x; idx < total;
         idx += (long)gridDim.x * 256) {
        int col = (int)(idx & 255);
        float mean = stats[col] * inv_n;
        float var = stats[256 + col] * inv_n - mean * mean;
        float sc = rsqrtf(var + BN_EPS) * gamma[col];
        float v = (x[idx] - mean) * sc + beta[col];
        if (TANH) v = tanhf(v);
        y[idx] = v;
    }
}

// BN apply writing bf16 hi/lo split directly (no fp32 output; no tanh).
__global__ __launch_bounds__(256) void bn_apply_split_kernel(
    const float* __restrict__ x, u16* __restrict__ hi, u16* __restrict__ lo,
    int n, const float* __restrict__ gamma, const float* __restrict__ beta,
    const float* __restrict__ stats) {
    long total = (long)n * 256;
    float inv_n = 1.f / (float)n;
    long idx = (long)blockIdx.x * 256 + threadIdx.x;
    if (idx >= total) return;
    int col = (int)(idx & 255);
    float mean = stats[col] * inv_n;
    float var = stats[256 + col] * inv_n - mean * mean;
    float sc = rsqrtf(var + BN_EPS) * gamma[col];
    float v = (x[idx] - mean) * sc + beta[col];
    u16 h = f2b(v);
    hi[idx] = h;
    lo[idx] = f2b(v - b2f(h));
}

// ---------------------------------------------------------------------------
// Quaternion vec-vec multiplication. X/R rows reconstructed from the shared
// xr bf16 hi/lo split (reconstruction error ~2^-17 — below GEMM path error).
// ---------------------------------------------------------------------------
__global__ __launch_bounds__(256) void hr_kernel(
    const u16* __restrict__ xhi, const u16* __restrict__ xlo,
    const int* __restrict__ e1_idx, const int* __restrict__ r_idx,
    float* __restrict__ hr) {
    int idx = blockIdx.x * 256 + threadIdx.x;
    if (idx >= BATCH * 64) return;
    int b = idx >> 6, s = idx & 63;
    long hrow = (long)e1_idx[b] * 256;
    long prow = ((long)N_ENTS + r_idx[b]) * 256;
    float qr = b2f(xhi[hrow + s])       + b2f(xlo[hrow + s]);
    float qi = b2f(xhi[hrow + 64 + s])  + b2f(xlo[hrow + 64 + s]);
    float qj = b2f(xhi[hrow + 128 + s]) + b2f(xlo[hrow + 128 + s]);
    float qk = b2f(xhi[hrow + 192 + s]) + b2f(xlo[hrow + 192 + s]);
    float pr = b2f(xhi[prow + s])       + b2f(xlo[prow + s]);
    float pi = b2f(xhi[prow + 64 + s])  + b2f(xlo[prow + 64 + s]);
    float pj = b2f(xhi[prow + 128 + s]) + b2f(xlo[prow + 128 + s]);
    float pk = b2f(xhi[prow + 192 + s]) + b2f(xlo[prow + 192 + s]);
    float inv = rsqrtf(pr * pr + pi * pi + pj * pj + pk * pk);
    pr *= inv; pi *= inv; pj *= inv; pk *= inv;
    float* o = hr + (long)b * 256 + s;
    o[0]   = qr * pr - qi * pi - qj * pj - qk * pk;
    o[64]  = qi * pr + qr * pi - qk * pj + qj * pk;
    o[128] = qj * pr + qk * pi + qr * pj - qi * pk;
    o[192] = qk * pr - qj * pi + qi * pj + qr * pk;
}

// ---------------------------------------------------------------------------
// Host-side orchestration
// ---------------------------------------------------------------------------
struct Csr {
    int* off;
    int* cur;
    int2* pack;
};

struct Ws {
    float* Gbuf;        // (50500,256) gather result
    float* aggA;        // (50500,256)
    float* aggB;        // (50000,256)
    float* hr;          // (512,256)
    float* stats;       // 512
    u16* xr_hi;         // (50500,256) bf16 split of current XR
    u16* xr_lo;
    u16* hrn_hi;        // (512,256)
    u16* hrn_lo;
    u16* ht_hi;         // (256,512) max
    u16* ht_lo;
    Csr adj;
    Csr adjr;
};

static void build_csr(const int* rows, const int* cols, const float* vals,
                      int n_rows, const Csr& c, hipStream_t stream) {
    hipMemsetAsync(c.cur, 0, (size_t)n_rows * sizeof(int), stream);
    hist_kernel<<<(NEDGE + 255) / 256, 256, 0, stream>>>(rows, c.cur, NEDGE);
    exscan_kernel<<<1, 1024, 0, stream>>>(c.cur, n_rows, c.off);
    hipMemcpyAsync(c.cur, c.off, (size_t)n_rows * sizeof(int),
                   hipMemcpyDeviceToDevice, stream);
    scatter_kernel<<<(NEDGE + 255) / 256, 256, 0, stream>>>(
        rows, cols, vals, c.cur, c.pack, NEDGE);
}

static void run_bn(float* buf, float* outbuf, int n, const float* gamma,
                   const float* beta, bool do_tanh, const Ws& w,
                   hipStream_t stream) {
    hipMemsetAsync(w.stats, 0, 512 * sizeof(float), stream);
    bn_stats_kernel<<<(n + 255) / 256, 256, 0, stream>>>(buf, n, w.stats);
    long total = (long)n * 256;
    int blocks = (int)((total + 255) / 256);
    if (blocks > 2048) blocks = 2048;
    if (do_tanh)
        bn_apply_kernel<true><<<blocks, 256, 0, stream>>>(buf, outbuf, n, gamma, beta, w.stats);
    else
        bn_apply_kernel<false><<<blocks, 256, 0, stream>>>(buf, outbuf, n, gamma, beta, w.stats);
}

static void run_split(const float* x, u16* hi, u16* lo, long n,
                      hipStream_t stream) {
    long n4 = n / 4;
    split_kernel<<<(int)((n4 + 255) / 256), 256, 0, stream>>>(x, hi, lo, n4);
}

static void run_q4gnn(int n, const Csr& c, const float* W, const float* gamma,
                      const float* beta, float* agg, const Ws& w,
                      hipStream_t stream) {
    // (A @ X) first: gather raw XR rows into G.
    int gblocks = (n * 64 + 255) / 256;
    csr_gather_kernel<<<gblocks, 256, 0, stream>>>(
        w.xr_hi, w.xr_lo, c.off, c.pack, w.Gbuf, n);
    // Then (A@X) @ H.
    build_ht_kernel<<<(256 * 256) / 256, 256, 0, stream>>>(W, w.ht_hi, w.ht_lo, 64);
    dim3 g(1, (n + 127) / 128);
    mfma_agg_kernel<<<g, 256, 0, stream>>>(w.Gbuf, w.ht_hi, w.ht_lo, agg, n);
    run_bn(agg, agg, n, gamma, beta, true, w, stream);
}

static void run_score(const int* e1_idx, const int* r_idx, const float* gamma,
                      const float* beta, float* out_l, const Ws& w,
                      hipStream_t stream) {
    hr_kernel<<<(BATCH * 64) / 256, 256, 0, stream>>>(
        w.xr_hi, w.xr_lo, e1_idx, r_idx, w.hr);
    hipMemsetAsync(w.stats, 0, 512 * sizeof(float), stream);
    bn_stats_kernel<<<(BATCH + 255) / 256, 256, 0, stream>>>(w.hr, BATCH, w.stats);
    bn_apply_split_kernel<<<(BATCH * 256) / 256, 256, 0, stream>>>(
        w.hr, w.hrn_hi, w.hrn_lo, BATCH, gamma, beta, w.stats);
    dim3 g((N_ENTS + 255) / 256, BATCH / 128);
    mfma_score_kernel<<<g, 256, 0, stream>>>(
        w.hrn_hi, w.hrn_lo, w.xr_hi, w.xr_lo, out_l);
}

extern "C" void kernel_launch(void* const* d_in, const int* in_sizes, int n_in,
                              void* d_out, int out_size, void* d_ws, size_t ws_size,
                              hipStream_t stream) {
    const int*   e1_idx     = (const int*)d_in[0];
    const int*   r_idx      = (const int*)d_in[1];
    const float* emb        = (const float*)d_in[2];
    const float* gcn1_w     = (const float*)d_in[3];
    const float* gcn2_w     = (const float*)d_in[4];
    const float* gcn1_gamma = (const float*)d_in[5];
    const float* gcn1_beta  = (const float*)d_in[6];
    const float* gcn2_gamma = (const float*)d_in[7];
    const float* gcn2_beta  = (const float*)d_in[8];
    const float* lin_ents   = (const float*)d_in[9];
    const float* bn_s_gamma = (const float*)d_in[10];
    const float* bn_s_beta  = (const float*)d_in[11];
    const int*   adj_rows   = (const int*)d_in[12];
    const int*   adj_cols   = (const int*)d_in[13];
    const float* adj_vals   = (const float*)d_in[14];
    const int*   adjr_rows  = (const int*)d_in[15];
    const int*   adjr_cols  = (const int*)d_in[16];
    const float* adjr_vals  = (const float*)d_in[17];
    float* out = (float*)d_out;

    Ws w;
    float* f = (float*)d_ws;
    w.Gbuf       = f; f += (long)N_ALL * EMB;
    w.aggA       = f; f += (long)N_ALL * EMB;
    w.aggB       = f; f += (long)N_ENTS * EMB;
    w.hr         = f; f += BATCH * EMB;
    w.stats      = f; f += 512;
    w.xr_hi  = (u16*)f; f += (long)N_ALL * EMB / 2;
    w.xr_lo  = (u16*)f; f += (long)N_ALL * EMB / 2;
    w.hrn_hi = (u16*)f; f += BATCH * EMB / 2;
    w.hrn_lo = (u16*)f; f += BATCH * EMB / 2;
    w.ht_hi  = (u16*)f; f += 256 * 512 / 2;
    w.ht_lo  = (u16*)f; f += 256 * 512 / 2;
    int* ip = (int*)f;
    w.adj.pack  = (int2*)ip; ip += 2 * NEDGE;
    w.adjr.pack = (int2*)ip; ip += 2 * NEDGE;
    w.adj.off    = ip; ip += N_ENTS + 1;
    w.adj.cur    = ip; ip += N_ENTS;
    w.adjr.off   = ip; ip += N_ALL + 1;
    w.adjr.cur   = ip; ip += N_ALL;

    // Build both CSRs once; reused by both layers.
    build_csr(adj_rows, adj_cols, adj_vals, N_ENTS, w.adj, stream);
    build_csr(adjr_rows, adjr_cols, adjr_vals, N_ALL, w.adjr, stream);

    // Split embeddings (entities+rels) once into the shared xr buffers.
    run_split(emb, w.xr_hi, w.xr_lo, (long)N_ALL * EMB, stream);

    // score 0
    run_score(e1_idx, r_idx, bn_s_gamma, bn_s_beta, out, w, stream);

    for (int l = 0; l < 2; l++) {
        run_q4gnn(N_ALL, w.adjr, gcn2_w + (long)l * 64 * 256,
                  gcn2_gamma + l * 256, gcn2_beta + l * 256, w.aggA, w, stream);
        run_q4gnn(N_ENTS, w.adj, gcn1_w + (long)l * 64 * 256,
                  gcn1_gamma + l * 256, gcn1_beta + l * 256, w.aggB, w, stream);
        build_ht_kernel<<<(256 * 512) / 256, 256, 0, stream>>>(
            lin_ents + (long)l * 128 * 256, w.ht_hi, w.ht_lo, 128);
        dim3 g(1, (N_ENTS + 127) / 128);
        mfma_lin_kernel<<<g, 256, 0, stream>>>(
            w.aggB, w.aggA, w.ht_hi, w.ht_lo, w.xr_hi, w.xr_lo, N_ENTS);
        // Rels rows: split the q4gnn R-update (aggA tail) into xr directly.
        run_split(w.aggA + (long)N_ENTS * EMB, w.xr_hi + (long)N_ENTS * EMB,
                  w.xr_lo + (long)N_ENTS * EMB, (long)N_RELS * EMB, stream);
        run_score(e1_idx, r_idx, bn_s_gamma + (l + 1) * 256,
                  bn_s_beta + (l + 1) * 256,
                  out + (long)(l + 1) * BATCH * N_ENTS, w, stream);
    }
}

// Round 10
// 1667.298 us; speedup vs baseline: 1.1330x; 1.1330x over previous
//
#include <hip/hip_runtime.h>
#include <math.h>

#define N_ENTS 50000
#define N_RELS 500
#define N_ALL  50500
#define EMB    256
#define NEDGE  400000
#define BATCH  512
#define BN_EPS 1e-5f

typedef unsigned short u16;
typedef unsigned int   u32;
typedef __attribute__((ext_vector_type(8))) short s16x8;  // 8 bf16 (4 VGPRs)
typedef __attribute__((ext_vector_type(4))) float f32x4;  // MFMA acc

// LDS row stride in u16 for 32-wide K tiles: 40 shorts = 80 B, 16B-aligned
// chunks, 20-bank-quad stride => <=2-way (free) conflicts on fragment reads.
#define LSTR 40

// ---------------------------------------------------------------------------
// bf16 split helpers (RNE). x = hi + lo with |x-hi-lo| ~ 2^-17|x|.
// ---------------------------------------------------------------------------
__device__ __forceinline__ u16 f2b(float x) {
    u32 u = __float_as_uint(x);
    return (u16)((u + 0x7fffu + ((u >> 16) & 1u)) >> 16);
}
__device__ __forceinline__ float b2f(u16 h) {
    return __uint_as_float((u32)h << 16);
}

// Split fp32 array into bf16 hi/lo arrays. n4 = count of float4 groups.
__global__ __launch_bounds__(256) void split_kernel(
    const float* __restrict__ x, u16* __restrict__ hi, u16* __restrict__ lo,
    long n4) {
    long i = (long)blockIdx.x * 256 + threadIdx.x;
    if (i >= n4) return;
    float4 v = ((const float4*)x)[i];
    u16 h0 = f2b(v.x), h1 = f2b(v.y), h2 = f2b(v.z), h3 = f2b(v.w);
    u16 l0 = f2b(v.x - b2f(h0)), l1 = f2b(v.y - b2f(h1));
    u16 l2 = f2b(v.z - b2f(h2)), l3 = f2b(v.w - b2f(h3));
    uint2 hp, lp;
    hp.x = (u32)h0 | ((u32)h1 << 16); hp.y = (u32)h2 | ((u32)h3 << 16);
    lp.x = (u32)l0 | ((u32)l1 << 16); lp.y = (u32)l2 | ((u32)l3 << 16);
    ((uint2*)hi)[i] = hp;
    ((uint2*)lo)[i] = lp;
}

// ---------------------------------------------------------------------------
// Build TRANSPOSED hamilton HT[n][k] (256 rows, K=4P cols), pre-split bf16.
// ---------------------------------------------------------------------------
__global__ __launch_bounds__(256) void build_ht_kernel(
    const float* __restrict__ W, u16* __restrict__ Hhi, u16* __restrict__ Hlo,
    int P) {
    int K4 = 4 * P;
    int idx = blockIdx.x * 256 + threadIdx.x;
    int total = 256 * K4;
    if (idx >= total) return;
    int n = idx / K4, k = idx - n * K4;
    int a = k / P, p = k - a * P;
    int c = n >> 6, s = n & 63;
    const int  comp[4][4] = {{0,1,2,3},{1,0,3,2},{2,3,0,1},{3,2,1,0}};
    const float sgn[4][4] = {{1.f,1.f,1.f,1.f},
                             {-1.f,1.f,1.f,-1.f},
                             {-1.f,-1.f,1.f,1.f},
                             {-1.f,1.f,-1.f,1.f}};
    float v = sgn[a][c] * W[p * 256 + comp[a][c] * 64 + s];
    u16 h = f2b(v);
    Hhi[idx] = h;
    Hlo[idx] = f2b(v - b2f(h));
}

// BN coefficient precompute: coef[col] = (sc, beta - mean*sc).
__global__ __launch_bounds__(256) void bn_coeff_kernel(
    const float* __restrict__ stats, int n, const float* __restrict__ gamma,
    const float* __restrict__ beta, float2* __restrict__ coef) {
    int col = threadIdx.x;
    float inv_n = 1.f / (float)n;
    float mean = stats[col] * inv_n;
    float var = stats[256 + col] * inv_n - mean * mean;
    float sc = rsqrtf(var + BN_EPS) * gamma[col];
    coef[col] = make_float2(sc, beta[col] - mean * sc);
}

// ---------------------------------------------------------------------------
// MFMA GEMM core (BT form): C[m][n] = sum_k A[m][k]*Bt[n][k].
// Block 256 thr = 4 waves as 2Mx2N, tile 128x256, wave tile 64x128.
// K-step 32, mfma_f32_16x16x32_bf16, split-bf16 3-term.
// ---------------------------------------------------------------------------
template <int ROWS>
__device__ __forceinline__ void stage_rows(
    const u16* __restrict__ Shi, const u16* __restrict__ Slo,
    long row0, int rows_left, int K, int k0,
    u16* __restrict__ Lh, u16* __restrict__ Ll, int tid) {
#pragma unroll
    for (int p = 0; p < ROWS / 64; p++) {
        int idx = tid + p * 256;
        int r = idx >> 2, c = idx & 3;
        uint4 vh = make_uint4(0, 0, 0, 0), vl = make_uint4(0, 0, 0, 0);
        if (r < rows_left) {
            long base = (row0 + r) * (long)K + k0 + c * 8;
            vh = *(const uint4*)&Shi[base];
            vl = *(const uint4*)&Slo[base];
        }
        *(uint4*)&Lh[r * LSTR + c * 8] = vh;
        *(uint4*)&Ll[r * LSTR + c * 8] = vl;
    }
}

// Stage 128 rows x 32 cols of an fp32 matrix, splitting to bf16 hi/lo in
// LDS on the fly (for fp32 A-operands).
__device__ __forceinline__ void stage_f32_split(
    const float* __restrict__ S, long row0, int rows_left, int K, int k0,
    u16* __restrict__ Lh, u16* __restrict__ Ll, int tid) {
#pragma unroll
    for (int p = 0; p < 4; p++) {
        int idx = tid + p * 256;
        int r = idx >> 3, c4 = idx & 7;
        float4 v = make_float4(0.f, 0.f, 0.f, 0.f);
        if (r < rows_left)
            v = *(const float4*)&S[(row0 + r) * (long)K + k0 + c4 * 4];
        u16 h0 = f2b(v.x), h1 = f2b(v.y), h2 = f2b(v.z), h3 = f2b(v.w);
        u16 l0 = f2b(v.x - b2f(h0)), l1 = f2b(v.y - b2f(h1));
        u16 l2 = f2b(v.z - b2f(h2)), l3 = f2b(v.w - b2f(h3));
        uint2 hp, lp;
        hp.x = (u32)h0 | ((u32)h1 << 16); hp.y = (u32)h2 | ((u32)h3 << 16);
        lp.x = (u32)l0 | ((u32)l1 << 16); lp.y = (u32)l2 | ((u32)l3 << 16);
        *(uint2*)&Lh[r * LSTR + c4 * 4] = hp;
        *(uint2*)&Ll[r * LSTR + c4 * 4] = lp;
    }
}

__device__ __forceinline__ void mfma_tile256(
    const u16* __restrict__ Ah, const u16* __restrict__ Al,
    const u16* __restrict__ Bh, const u16* __restrict__ Bl,
    int wm, int wn, int lane, f32x4 acc[4][8]) {
    int lr = lane & 15, kg = lane >> 4;
    s16x8 ah[4], al[4];
#pragma unroll
    for (int fm = 0; fm < 4; fm++) {
        int off = (wm + fm * 16 + lr) * LSTR + kg * 8;
        ah[fm] = *(const s16x8*)&Ah[off];
        al[fm] = *(const s16x8*)&Al[off];
    }
#pragma unroll
    for (int fn = 0; fn < 8; fn++) {
        int off = (wn + fn * 16 + lr) * LSTR + kg * 8;
        s16x8 bh = *(const s16x8*)&Bh[off];
        s16x8 bl = *(const s16x8*)&Bl[off];
#pragma unroll
        for (int fm = 0; fm < 4; fm++) {
            acc[fm][fn] = __builtin_amdgcn_mfma_f32_16x16x32_bf16(
                ah[fm], bh, acc[fm][fn], 0, 0, 0);
            acc[fm][fn] = __builtin_amdgcn_mfma_f32_16x16x32_bf16(
                ah[fm], bl, acc[fm][fn], 0, 0, 0);
            acc[fm][fn] = __builtin_amdgcn_mfma_f32_16x16x32_bf16(
                al[fm], bh, acc[fm][fn], 0, 0, 0);
        }
    }
}

// Agg GEMM: agg[M,256] = G[M,256] @ HT^T, fp32 out, PLUS fused BN stats:
// column sum/sumsq accumulated from the register accumulator (shfl-reduce
// over the 4 lq lane-groups, atomicAdd per col per wave). Tail rows >= M
// have zero A-staging -> acc 0 -> contribute 0 to stats.
__global__ __launch_bounds__(256, 2) void mfma_agg_kernel(
    const float* __restrict__ G,
    const u16* __restrict__ Bhi, const u16* __restrict__ Blo,
    float* __restrict__ C, float* __restrict__ stats, int M) {
    __shared__ u16 Ah[128 * LSTR], Al[128 * LSTR];
    __shared__ u16 Bh[256 * LSTR], Bl[256 * LSTR];
    int tid = threadIdx.x, lane = tid & 63, wid = tid >> 6;
    int wm = (wid >> 1) * 64, wn = (wid & 1) * 128;
    long bm0 = (long)blockIdx.y * 128;   // gridDim.x == 1 (N=256)
    int rA = (int)(((long)M - bm0 < 128) ? (long)M - bm0 : 128);
    f32x4 acc[4][8] = {};
    for (int k0 = 0; k0 < 256; k0 += 32) {
        if (k0) __syncthreads();
        stage_f32_split(G, bm0, rA, 256, k0, Ah, Al, tid);
        stage_rows<256>(Bhi, Blo, 0, 256, 256, k0, Bh, Bl, tid);
        __syncthreads();
        mfma_tile256(Ah, Al, Bh, Bl, wm, wn, lane, acc);
    }
    int lr = lane & 15, lq = lane >> 4;
#pragma unroll
    for (int fm = 0; fm < 4; fm++) {
#pragma unroll
        for (int r = 0; r < 4; r++) {
            long row = bm0 + wm + fm * 16 + lq * 4 + r;
            if (row < M) {
#pragma unroll
                for (int fn = 0; fn < 8; fn++) {
                    long col = wn + fn * 16 + lr;
                    C[row * 256 + col] = acc[fm][fn][r];
                }
            }
        }
    }
    // Fused BN stats.
#pragma unroll
    for (int fn = 0; fn < 8; fn++) {
        float s = 0.f, sq = 0.f;
#pragma unroll
        for (int fm = 0; fm < 4; fm++)
#pragma unroll
            for (int r = 0; r < 4; r++) {
                float v = acc[fm][fn][r];
                s += v;
                sq += v * v;
            }
        s += __shfl_xor(s, 16);  s += __shfl_xor(s, 32);
        sq += __shfl_xor(sq, 16); sq += __shfl_xor(sq, 32);
        if (lane < 16) {
            int col = wn + fn * 16 + lr;
            atomicAdd(&stats[col], s);
            atomicAdd(&stats[256 + col], sq);
        }
    }
}

// Score GEMM: A=hrn split (512x256), Bt=X split (50000x256), sigmoid out.
__global__ __launch_bounds__(256, 2) void mfma_score_kernel(
    const u16* __restrict__ Ahi, const u16* __restrict__ Alo,
    const u16* __restrict__ Bhi, const u16* __restrict__ Blo,
    float* __restrict__ out) {
    __shared__ u16 Ah[128 * LSTR], Al[128 * LSTR];
    __shared__ u16 Bh[256 * LSTR], Bl[256 * LSTR];
    int tid = threadIdx.x, lane = tid & 63, wid = tid >> 6;
    int wm = (wid >> 1) * 64, wn = (wid & 1) * 128;
    long bm0 = (long)blockIdx.y * 128, bn0 = (long)blockIdx.x * 256;
    int rB = (int)(((long)N_ENTS - bn0 < 256) ? (long)N_ENTS - bn0 : 256);
    f32x4 acc[4][8] = {};
    for (int k0 = 0; k0 < 256; k0 += 32) {
        if (k0) __syncthreads();
        stage_rows<128>(Ahi, Alo, bm0, 128, 256, k0, Ah, Al, tid);
        stage_rows<256>(Bhi, Blo, bn0, rB, 256, k0, Bh, Bl, tid);
        __syncthreads();
        mfma_tile256(Ah, Al, Bh, Bl, wm, wn, lane, acc);
    }
    int lr = lane & 15, lq = lane >> 4;
#pragma unroll
    for (int fm = 0; fm < 4; fm++) {
#pragma unroll
        for (int r = 0; r < 4; r++) {
            long row = bm0 + wm + fm * 16 + lq * 4 + r;  // < 512 always
#pragma unroll
            for (int fn = 0; fn < 8; fn++) {
                long col = bn0 + wn + fn * 16 + lr;
                if (col < N_ENTS) {
                    float v = acc[fm][fn][r];
                    out[row * N_ENTS + col] = 1.f / (1.f + __expf(-v));
                }
            }
        }
    }
}

// Lin GEMM: Xcat[50000,512] @ H512 with BN+tanh FUSED into the A-loader:
// A raw values come from aggB (Xef) / aggA (Xrf); apply tanh(v*sc+off)
// using precomputed per-column coefficients, then split to bf16 in LDS.
// (Each agg element is staged exactly once -> tanh count conserved.)
// Epilogue writes ONLY the bf16 hi/lo split of the result.
__global__ __launch_bounds__(256, 2) void mfma_lin_kernel(
    const float* __restrict__ Xef, const float* __restrict__ Xrf,
    const float2* __restrict__ coefE, const float2* __restrict__ coefR,
    const u16* __restrict__ Bhi, const u16* __restrict__ Blo,
    u16* __restrict__ Chi, u16* __restrict__ Clo, int M) {
    __shared__ u16 Ah[128 * LSTR], Al[128 * LSTR];
    __shared__ u16 Bh[256 * LSTR], Bl[256 * LSTR];
    int tid = threadIdx.x, lane = tid & 63, wid = tid >> 6;
    int wm = (wid >> 1) * 64, wn = (wid & 1) * 128;
    int bm0 = blockIdx.y * 128;   // gridDim.x == 1 (N=256)
    f32x4 acc[4][8] = {};
    for (int k0 = 0; k0 < 512; k0 += 32) {
        if (k0) __syncthreads();
#pragma unroll
        for (int p = 0; p < 4; p++) {
            int idx = tid + p * 256;
            int r = idx >> 3, c4 = idx & 7;
            int kk = k0 + c4 * 4;          // float4 never crosses a 64-chunk
            int chunk = kk >> 6, s = kk & 63;
            int gm = bm0 + r;
            const float* src = (chunk & 1) ? Xrf : Xef;
            const float2* cf = (chunk & 1) ? coefR : coefE;
            int base = (chunk >> 1) * 64 + s;
            float4 v = make_float4(0.f, 0.f, 0.f, 0.f);
            if (gm < M) v = *(const float4*)&src[(long)gm * 256 + base];
            float2 c0 = cf[base], c1 = cf[base + 1];
            float2 c2 = cf[base + 2], c3 = cf[base + 3];
            // BN + tanh (rows >= M give tanh(off): harmless, C rows guarded).
            v.x = tanhf(fmaf(v.x, c0.x, c0.y));
            v.y = tanhf(fmaf(v.y, c1.x, c1.y));
            v.z = tanhf(fmaf(v.z, c2.x, c2.y));
            v.w = tanhf(fmaf(v.w, c3.x, c3.y));
            u16 h0 = f2b(v.x), h1 = f2b(v.y), h2 = f2b(v.z), h3 = f2b(v.w);
            u16 l0 = f2b(v.x - b2f(h0)), l1 = f2b(v.y - b2f(h1));
            u16 l2 = f2b(v.z - b2f(h2)), l3 = f2b(v.w - b2f(h3));
            uint2 hp, lp;
            hp.x = (u32)h0 | ((u32)h1 << 16); hp.y = (u32)h2 | ((u32)h3 << 16);
            lp.x = (u32)l0 | ((u32)l1 << 16); lp.y = (u32)l2 | ((u32)l3 << 16);
            *(uint2*)&Ah[r * LSTR + c4 * 4] = hp;
            *(uint2*)&Al[r * LSTR + c4 * 4] = lp;
        }
        stage_rows<256>(Bhi, Blo, 0, 256, 512, k0, Bh, Bl, tid);
        __syncthreads();
        mfma_tile256(Ah, Al, Bh, Bl, wm, wn, lane, acc);
    }
    int lr = lane & 15, lq = lane >> 4;
#pragma unroll
    for (int fm = 0; fm < 4; fm++) {
#pragma unroll
        for (int r = 0; r < 4; r++) {
            long row = (long)bm0 + wm + fm * 16 + lq * 4 + r;
            if (row < M) {
#pragma unroll
                for (int fn = 0; fn < 8; fn++) {
                    long col = wn + fn * 16 + lr;
                    float v = acc[fm][fn][r];
                    u16 h = f2b(v);
                    Chi[row * 256 + col] = h;
                    Clo[row * 256 + col] = f2b(v - b2f(h));
                }
            }
        }
    }
}

// ---------------------------------------------------------------------------
// CSR build: histogram, single-block exclusive scan, ticket scatter.
// ---------------------------------------------------------------------------
__global__ __launch_bounds__(256) void hist_kernel(
    const int* __restrict__ rows, int* __restrict__ cnt, int n_edges) {
    int e = blockIdx.x * 256 + threadIdx.x;
    if (e < n_edges) atomicAdd(&cnt[rows[e]], 1);
}

__global__ __launch_bounds__(1024) void exscan_kernel(
    const int* __restrict__ cnt, int n, int* __restrict__ off) {
    __shared__ int part[1024];
    int t = threadIdx.x;
    int chunk = (n + 1023) / 1024;
    int lo = t * chunk;
    int hi = lo + chunk; if (hi > n) hi = n;
    int s = 0;
    for (int i = lo; i < hi; i++) s += cnt[i];
    part[t] = s;
    __syncthreads();
    for (int d = 1; d < 1024; d <<= 1) {
        int v = (t >= d) ? part[t - d] : 0;
        __syncthreads();
        part[t] += v;
        __syncthreads();
    }
    int base = (t == 0) ? 0 : part[t - 1];
    for (int i = lo; i < hi; i++) {
        off[i] = base;
        base += cnt[i];
    }
    if (hi >= n) off[n] = base;
}

__global__ __launch_bounds__(256) void scatter_kernel(
    const int* __restrict__ rows, const int* __restrict__ cols,
    const float* __restrict__ vals, int* __restrict__ cursor,
    int2* __restrict__ pack, int n_edges) {
    int e = blockIdx.x * 256 + threadIdx.x;
    if (e >= n_edges) return;
    int r = rows[e];
    int p = atomicAdd(&cursor[r], 1);
    pack[p] = make_int2(cols[e], __float_as_int(vals[e]));
}

// ---------------------------------------------------------------------------
// CSR gather-aggregate over the XR bf16 split ((A@X) form):
// G[row,:] = sum_e vals[e] * (xhi[cols[e],:]+xlo[cols[e],:]).
// ---------------------------------------------------------------------------
__global__ __launch_bounds__(256) void csr_gather_kernel(
    const u16* __restrict__ xhi, const u16* __restrict__ xlo,
    const int* __restrict__ off, const int2* __restrict__ pack,
    float* __restrict__ G, int n_rows) {
    int gid = blockIdx.x * 256 + threadIdx.x;
    int row = gid >> 6;
    int lane = gid & 63;
    if (row >= n_rows) return;
    int beg = off[row], end = off[row + 1];
    float4 acc = {0.f, 0.f, 0.f, 0.f};
    int e = beg;
    for (; e + 4 <= end; e += 4) {
        int2 cv0 = pack[e], cv1 = pack[e + 1], cv2 = pack[e + 2], cv3 = pack[e + 3];
        long b0 = (long)cv0.x * 256 + lane * 4;
        long b1 = (long)cv1.x * 256 + lane * 4;
        long b2 = (long)cv2.x * 256 + lane * 4;
        long b3 = (long)cv3.x * 256 + lane * 4;
        uint2 h0 = *(const uint2*)(xhi + b0), l0 = *(const uint2*)(xlo + b0);
        uint2 h1 = *(const uint2*)(xhi + b1), l1 = *(const uint2*)(xlo + b1);
        uint2 h2 = *(const uint2*)(xhi + b2), l2 = *(const uint2*)(xlo + b2);
        uint2 h3 = *(const uint2*)(xhi + b3), l3 = *(const uint2*)(xlo + b3);
        float v0 = __int_as_float(cv0.y), v1 = __int_as_float(cv1.y);
        float v2 = __int_as_float(cv2.y), v3 = __int_as_float(cv3.y);
        acc.x = fmaf(v0, b2f((u16)(h0.x & 0xffff)) + b2f((u16)(l0.x & 0xffff)), acc.x);
        acc.y = fmaf(v0, b2f((u16)(h0.x >> 16))    + b2f((u16)(l0.x >> 16)),    acc.y);
        acc.z = fmaf(v0, b2f((u16)(h0.y & 0xffff)) + b2f((u16)(l0.y & 0xffff)), acc.z);
        acc.w = fmaf(v0, b2f((u16)(h0.y >> 16))    + b2f((u16)(l0.y >> 16)),    acc.w);
        acc.x = fmaf(v1, b2f((u16)(h1.x & 0xffff)) + b2f((u16)(l1.x & 0xffff)), acc.x);
        acc.y = fmaf(v1, b2f((u16)(h1.x >> 16))    + b2f((u16)(l1.x >> 16)),    acc.y);
        acc.z = fmaf(v1, b2f((u16)(h1.y & 0xffff)) + b2f((u16)(l1.y & 0xffff)), acc.z);
        acc.w = fmaf(v1, b2f((u16)(h1.y >> 16))    + b2f((u16)(l1.y >> 16)),    acc.w);
        acc.x = fmaf(v2, b2f((u16)(h2.x & 0xffff)) + b2f((u16)(l2.x & 0xffff)), acc.x);
        acc.y = fmaf(v2, b2f((u16)(h2.x >> 16))    + b2f((u16)(l2.x >> 16)),    acc.y);
        acc.z = fmaf(v2, b2f((u16)(h2.y & 0xffff)) + b2f((u16)(l2.y & 0xffff)), acc.z);
        acc.w = fmaf(v2, b2f((u16)(h2.y >> 16))    + b2f((u16)(l2.y >> 16)),    acc.w);
        acc.x = fmaf(v3, b2f((u16)(h3.x & 0xffff)) + b2f((u16)(l3.x & 0xffff)), acc.x);
        acc.y = fmaf(v3, b2f((u16)(h3.x >> 16))    + b2f((u16)(l3.x >> 16)),    acc.y);
        acc.z = fmaf(v3, b2f((u16)(h3.y & 0xffff)) + b2f((u16)(l3.y & 0xffff)), acc.z);
        acc.w = fmaf(v3, b2f((u16)(h3.y >> 16))    + b2f((u16)(l3.y >> 16)),    acc.w);
    }
    for (; e < end; e++) {
        int2 cv = pack[e];
        float v = __int_as_float(cv.y);
        long b = (long)cv.x * 256 + lane * 4;
        uint2 hv = *(const uint2*)(xhi + b), lv = *(const uint2*)(xlo + b);
        acc.x = fmaf(v, b2f((u16)(hv.x & 0xffff)) + b2f((u16)(lv.x & 0xffff)), acc.x);
        acc.y = fmaf(v, b2f((u16)(hv.x >> 16))    + b2f((u16)(lv.x >> 16)),    acc.y);
        acc.z = fmaf(v, b2f((u16)(hv.y & 0xffff)) + b2f((u16)(lv.y & 0xffff)), acc.z);
        acc.w = fmaf(v, b2f((u16)(hv.y >> 16))    + b2f((u16)(lv.y >> 16)),    acc.w);
    }
    *(float4*)(G + (long)row * 256 + lane * 4) = acc;
}

// ---------------------------------------------------------------------------
// BN stats (hr path only) + BN apply-split (hr) + rels-tail BN+tanh+split
// ---------------------------------------------------------------------------
__global__ __launch_bounds__(256) void bn_stats_kernel(
    const float* __restrict__ x, int n, float* __restrict__ stats) {
    int col = threadIdx.x;
    int r0 = blockIdx.x * 256;
    int r1 = r0 + 256;
    if (r1 > n) r1 = n;
    float s = 0.f, sq = 0.f;
    for (int r = r0; r < r1; r++) {
        float v = x[(long)r * 256 + col];
        s += v;
        sq += v * v;
    }
    atomicAdd(&stats[col], s);
    atomicAdd(&stats[256 + col], sq);
}

// BN apply writing bf16 hi/lo split directly (hr path; no tanh).
__global__ __launch_bounds__(256) void bn_apply_split_kernel(
    const float* __restrict__ x, u16* __restrict__ hi, u16* __restrict__ lo,
    int n, const float* __restrict__ gamma, const float* __restrict__ beta,
    const float* __restrict__ stats) {
    long total = (long)n * 256;
    float inv_n = 1.f / (float)n;
    long idx = (long)blockIdx.x * 256 + threadIdx.x;
    if (idx >= total) return;
    int col = (int)(idx & 255);
    float mean = stats[col] * inv_n;
    float var = stats[256 + col] * inv_n - mean * mean;
    float sc = rsqrtf(var + BN_EPS) * gamma[col];
    float v = (x[idx] - mean) * sc + beta[col];
    u16 h = f2b(v);
    hi[idx] = h;
    lo[idx] = f2b(v - b2f(h));
}

// Rels tail: BN+tanh from coef, then split to xr bf16 buffers.
__global__ __launch_bounds__(256) void bn_tanh_split_kernel(
    const float* __restrict__ x, const float2* __restrict__ coef,
    u16* __restrict__ hi, u16* __restrict__ lo, long total) {
    long idx = (long)blockIdx.x * 256 + threadIdx.x;
    if (idx >= total) return;
    int col = (int)(idx & 255);
    float2 c = coef[col];
    float v = tanhf(fmaf(x[idx], c.x, c.y));
    u16 h = f2b(v);
    hi[idx] = h;
    lo[idx] = f2b(v - b2f(h));
}

// ---------------------------------------------------------------------------
// Quaternion vec-vec multiplication (reads xr split, err ~2^-17).
// ---------------------------------------------------------------------------
__global__ __launch_bounds__(256) void hr_kernel(
    const u16* __restrict__ xhi, const u16* __restrict__ xlo,
    const int* __restrict__ e1_idx, const int* __restrict__ r_idx,
    float* __restrict__ hr) {
    int idx = blockIdx.x * 256 + threadIdx.x;
    if (idx >= BATCH * 64) return;
    int b = idx >> 6, s = idx & 63;
    long hrow = (long)e1_idx[b] * 256;
    long prow = ((long)N_ENTS + r_idx[b]) * 256;
    float qr = b2f(xhi[hrow + s])       + b2f(xlo[hrow + s]);
    float qi = b2f(xhi[hrow + 64 + s])  + b2f(xlo[hrow + 64 + s]);
    float qj = b2f(xhi[hrow + 128 + s]) + b2f(xlo[hrow + 128 + s]);
    float qk = b2f(xhi[hrow + 192 + s]) + b2f(xlo[hrow + 192 + s]);
    float pr = b2f(xhi[prow + s])       + b2f(xlo[prow + s]);
    float pi = b2f(xhi[prow + 64 + s])  + b2f(xlo[prow + 64 + s]);
    float pj = b2f(xhi[prow + 128 + s]) + b2f(xlo[prow + 128 + s]);
    float pk = b2f(xhi[prow + 192 + s]) + b2f(xlo[prow + 192 + s]);
    float inv = rsqrtf(pr * pr + pi * pi + pj * pj + pk * pk);
    pr *= inv; pi *= inv; pj *= inv; pk *= inv;
    float* o = hr + (long)b * 256 + s;
    o[0]   = qr * pr - qi * pi - qj * pj - qk * pk;
    o[64]  = qi * pr + qr * pi - qk * pj + qj * pk;
    o[128] = qj * pr + qk * pi + qr * pj - qi * pk;
    o[192] = qk * pr - qj * pi + qi * pj + qr * pk;
}

// ---------------------------------------------------------------------------
// Host-side orchestration
// ---------------------------------------------------------------------------
struct Csr {
    int* off;
    int* cur;
    int2* pack;
};

struct Ws {
    float* Gbuf;        // (50500,256) gather result
    float* aggA;        // (50500,256) raw gcn2 output (pre-BN)
    float* aggB;        // (50000,256) raw gcn1 output (pre-BN)
    float* hr;          // (512,256)
    float* statsHr;     // 512
    float* statsA;      // 512
    float* statsB;      // 512
    float2* coefA;      // 256
    float2* coefB;      // 256
    u16* xr_hi;         // (50500,256) bf16 split of current XR
    u16* xr_lo;
    u16* hrn_hi;        // (512,256)
    u16* hrn_lo;
    u16* ht_hi;         // (256,512) max
    u16* ht_lo;
    Csr adj;
    Csr adjr;
};

static void build_csr(const int* rows, const int* cols, const float* vals,
                      int n_rows, const Csr& c, hipStream_t stream) {
    hipMemsetAsync(c.cur, 0, (size_t)n_rows * sizeof(int), stream);
    hist_kernel<<<(NEDGE + 255) / 256, 256, 0, stream>>>(rows, c.cur, NEDGE);
    exscan_kernel<<<1, 1024, 0, stream>>>(c.cur, n_rows, c.off);
    hipMemcpyAsync(c.cur, c.off, (size_t)n_rows * sizeof(int),
                   hipMemcpyDeviceToDevice, stream);
    scatter_kernel<<<(NEDGE + 255) / 256, 256, 0, stream>>>(
        rows, cols, vals, c.cur, c.pack, NEDGE);
}

static void run_split(const float* x, u16* hi, u16* lo, long n,
                      hipStream_t stream) {
    long n4 = n / 4;
    split_kernel<<<(int)((n4 + 255) / 256), 256, 0, stream>>>(x, hi, lo, n4);
}

// gather -> agg GEMM (+fused stats) -> coef. Output agg stays RAW (pre-BN);
// BN+tanh is applied by consumers via coef.
static void run_q4gnn(int n, const Csr& c, const float* W,
                      const float* gamma, const float* beta,
                      float* agg, float* stats, float2* coef,
                      const Ws& w, hipStream_t stream) {
    hipMemsetAsync(stats, 0, 512 * sizeof(float), stream);
    int gblocks = (n * 64 + 255) / 256;
    csr_gather_kernel<<<gblocks, 256, 0, stream>>>(
        w.xr_hi, w.xr_lo, c.off, c.pack, w.Gbuf, n);
    build_ht_kernel<<<(256 * 256) / 256, 256, 0, stream>>>(W, w.ht_hi, w.ht_lo, 64);
    dim3 g(1, (n + 127) / 128);
    mfma_agg_kernel<<<g, 256, 0, stream>>>(w.Gbuf, w.ht_hi, w.ht_lo, agg, stats, n);
    bn_coeff_kernel<<<1, 256, 0, stream>>>(stats, n, gamma, beta, coef);
}

static void run_score(const int* e1_idx, const int* r_idx, const float* gamma,
                      const float* beta, float* out_l, const Ws& w,
                      hipStream_t stream) {
    hr_kernel<<<(BATCH * 64) / 256, 256, 0, stream>>>(
        w.xr_hi, w.xr_lo, e1_idx, r_idx, w.hr);
    hipMemsetAsync(w.statsHr, 0, 512 * sizeof(float), stream);
    bn_stats_kernel<<<(BATCH + 255) / 256, 256, 0, stream>>>(w.hr, BATCH, w.statsHr);
    bn_apply_split_kernel<<<(BATCH * 256) / 256, 256, 0, stream>>>(
        w.hr, w.hrn_hi, w.hrn_lo, BATCH, gamma, beta, w.statsHr);
    dim3 g((N_ENTS + 255) / 256, BATCH / 128);
    mfma_score_kernel<<<g, 256, 0, stream>>>(
        w.hrn_hi, w.hrn_lo, w.xr_hi, w.xr_lo, out_l);
}

extern "C" void kernel_launch(void* const* d_in, const int* in_sizes, int n_in,
                              void* d_out, int out_size, void* d_ws, size_t ws_size,
                              hipStream_t stream) {
    const int*   e1_idx     = (const int*)d_in[0];
    const int*   r_idx      = (const int*)d_in[1];
    const float* emb        = (const float*)d_in[2];
    const float* gcn1_w     = (const float*)d_in[3];
    const float* gcn2_w     = (const float*)d_in[4];
    const float* gcn1_gamma = (const float*)d_in[5];
    const float* gcn1_beta  = (const float*)d_in[6];
    const float* gcn2_gamma = (const float*)d_in[7];
    const float* gcn2_beta  = (const float*)d_in[8];
    const float* lin_ents   = (const float*)d_in[9];
    const float* bn_s_gamma = (const float*)d_in[10];
    const float* bn_s_beta  = (const float*)d_in[11];
    const int*   adj_rows   = (const int*)d_in[12];
    const int*   adj_cols   = (const int*)d_in[13];
    const float* adj_vals   = (const float*)d_in[14];
    const int*   adjr_rows  = (const int*)d_in[15];
    const int*   adjr_cols  = (const int*)d_in[16];
    const float* adjr_vals  = (const float*)d_in[17];
    float* out = (float*)d_out;

    Ws w;
    float* f = (float*)d_ws;
    w.Gbuf       = f; f += (long)N_ALL * EMB;
    w.aggA       = f; f += (long)N_ALL * EMB;
    w.aggB       = f; f += (long)N_ENTS * EMB;
    w.hr         = f; f += BATCH * EMB;
    w.statsHr    = f; f += 512;
    w.statsA     = f; f += 512;
    w.statsB     = f; f += 512;
    w.coefA      = (float2*)f; f += 512;
    w.coefB      = (float2*)f; f += 512;
    w.xr_hi  = (u16*)f; f += (long)N_ALL * EMB / 2;
    w.xr_lo  = (u16*)f; f += (long)N_ALL * EMB / 2;
    w.hrn_hi = (u16*)f; f += BATCH * EMB / 2;
    w.hrn_lo = (u16*)f; f += BATCH * EMB / 2;
    w.ht_hi  = (u16*)f; f += 256 * 512 / 2;
    w.ht_lo  = (u16*)f; f += 256 * 512 / 2;
    int* ip = (int*)f;
    w.adj.pack  = (int2*)ip; ip += 2 * NEDGE;
    w.adjr.pack = (int2*)ip; ip += 2 * NEDGE;
    w.adj.off    = ip; ip += N_ENTS + 1;
    w.adj.cur    = ip; ip += N_ENTS;
    w.adjr.off   = ip; ip += N_ALL + 1;
    w.adjr.cur   = ip; ip += N_ALL;

    // Build both CSRs once; reused by both layers.
    build_csr(adj_rows, adj_cols, adj_vals, N_ENTS, w.adj, stream);
    build_csr(adjr_rows, adjr_cols, adjr_vals, N_ALL, w.adjr, stream);

    // Split embeddings (entities+rels) once into the shared xr buffers.
    run_split(emb, w.xr_hi, w.xr_lo, (long)N_ALL * EMB, stream);

    // score 0
    run_score(e1_idx, r_idx, bn_s_gamma, bn_s_beta, out, w, stream);

    for (int l = 0; l < 2; l++) {
        run_q4gnn(N_ALL, w.adjr, gcn2_w + (long)l * 64 * 256,
                  gcn2_gamma + l * 256, gcn2_beta + l * 256,
                  w.aggA, w.statsA, w.coefA, w, stream);
        run_q4gnn(N_ENTS, w.adj, gcn1_w + (long)l * 64 * 256,
                  gcn1_gamma + l * 256, gcn1_beta + l * 256,
                  w.aggB, w.statsB, w.coefB, w, stream);
        build_ht_kernel<<<(256 * 512) / 256, 256, 0, stream>>>(
            lin_ents + (long)l * 128 * 256, w.ht_hi, w.ht_lo, 128);
        dim3 g(1, (N_ENTS + 127) / 128);
        mfma_lin_kernel<<<g, 256, 0, stream>>>(
            w.aggB, w.aggA, w.coefB, w.coefA, w.ht_hi, w.ht_lo,
            w.xr_hi, w.xr_lo, N_ENTS);
        // Rels tail: BN+tanh (gcn2 coef) + split into xr directly.
        bn_tanh_split_kernel<<<(N_RELS * EMB + 255) / 256, 256, 0, stream>>>(
            w.aggA + (long)N_ENTS * EMB, w.coefA,
            w.xr_hi + (long)N_ENTS * EMB, w.xr_lo + (long)N_ENTS * EMB,
            (long)N_RELS * EMB);
        run_score(e1_idx, r_idx, bn_s_gamma + (l + 1) * 256,
                  bn_s_beta + (l + 1) * 256,
                  out + (long)(l + 1) * BATCH * N_ENTS, w, stream);
    }
}

// Round 11
// 1634.237 us; speedup vs baseline: 1.1559x; 1.0202x over previous
//
#include <hip/hip_runtime.h>
#include <math.h>

#define N_ENTS 50000
#define N_RELS 500
#define N_ALL  50500
#define EMB    256
#define NEDGE  400000
#define BATCH  512
#define BN_EPS 1e-5f

typedef unsigned short u16;
typedef unsigned int   u32;
typedef __attribute__((ext_vector_type(8))) short s16x8;  // 8 bf16 (4 VGPRs)
typedef __attribute__((ext_vector_type(4))) float f32x4;  // MFMA acc

// LDS row stride in u16 for 32-wide K tiles: 40 shorts = 80 B, 16B-aligned
// chunks, 20-bank-quad stride => <=2-way (free) conflicts on fragment reads.
#define LSTR 40

// ---------------------------------------------------------------------------
// bf16 split helpers (RNE). x = hi + lo with |x-hi-lo| ~ 2^-17|x|.
// ---------------------------------------------------------------------------
__device__ __forceinline__ u16 f2b(float x) {
    u32 u = __float_as_uint(x);
    return (u16)((u + 0x7fffu + ((u >> 16) & 1u)) >> 16);
}
__device__ __forceinline__ float b2f(u16 h) {
    return __uint_as_float((u32)h << 16);
}

// Split fp32 array into bf16 hi/lo arrays. n4 = count of float4 groups.
__global__ __launch_bounds__(256) void split_kernel(
    const float* __restrict__ x, u16* __restrict__ hi, u16* __restrict__ lo,
    long n4) {
    long i = (long)blockIdx.x * 256 + threadIdx.x;
    if (i >= n4) return;
    float4 v = ((const float4*)x)[i];
    u16 h0 = f2b(v.x), h1 = f2b(v.y), h2 = f2b(v.z), h3 = f2b(v.w);
    u16 l0 = f2b(v.x - b2f(h0)), l1 = f2b(v.y - b2f(h1));
    u16 l2 = f2b(v.z - b2f(h2)), l3 = f2b(v.w - b2f(h3));
    uint2 hp, lp;
    hp.x = (u32)h0 | ((u32)h1 << 16); hp.y = (u32)h2 | ((u32)h3 << 16);
    lp.x = (u32)l0 | ((u32)l1 << 16); lp.y = (u32)l2 | ((u32)l3 << 16);
    ((uint2*)hi)[i] = hp;
    ((uint2*)lo)[i] = lp;
}

// ---------------------------------------------------------------------------
// Build TRANSPOSED hamilton HT[n][k] (256 rows, K=4P cols), pre-split bf16.
// ---------------------------------------------------------------------------
__global__ __launch_bounds__(256) void build_ht_kernel(
    const float* __restrict__ W, u16* __restrict__ Hhi, u16* __restrict__ Hlo,
    int P) {
    int K4 = 4 * P;
    int idx = blockIdx.x * 256 + threadIdx.x;
    int total = 256 * K4;
    if (idx >= total) return;
    int n = idx / K4, k = idx - n * K4;
    int a = k / P, p = k - a * P;
    int c = n >> 6, s = n & 63;
    const int  comp[4][4] = {{0,1,2,3},{1,0,3,2},{2,3,0,1},{3,2,1,0}};
    const float sgn[4][4] = {{1.f,1.f,1.f,1.f},
                             {-1.f,1.f,1.f,-1.f},
                             {-1.f,-1.f,1.f,1.f},
                             {-1.f,1.f,-1.f,1.f}};
    float v = sgn[a][c] * W[p * 256 + comp[a][c] * 64 + s];
    u16 h = f2b(v);
    Hhi[idx] = h;
    Hlo[idx] = f2b(v - b2f(h));
}

// BN coefficient precompute: coef[col] = (sc, beta - mean*sc).
__global__ __launch_bounds__(256) void bn_coeff_kernel(
    const float* __restrict__ stats, int n, const float* __restrict__ gamma,
    const float* __restrict__ beta, float2* __restrict__ coef) {
    int col = threadIdx.x;
    float inv_n = 1.f / (float)n;
    float mean = stats[col] * inv_n;
    float var = stats[256 + col] * inv_n - mean * mean;
    float sc = rsqrtf(var + BN_EPS) * gamma[col];
    coef[col] = make_float2(sc, beta[col] - mean * sc);
}

// ---------------------------------------------------------------------------
// MFMA GEMM core (BT form): C[m][n] = sum_k A[m][k]*Bt[n][k].
// Block 256 thr = 4 waves as 2Mx2N, tile 128x256, wave tile 64x128.
// K-step 32, mfma_f32_16x16x32_bf16, split-bf16 3-term.
// ---------------------------------------------------------------------------
template <int ROWS>
__device__ __forceinline__ void stage_rows(
    const u16* __restrict__ Shi, const u16* __restrict__ Slo,
    long row0, int rows_left, int K, int k0,
    u16* __restrict__ Lh, u16* __restrict__ Ll, int tid) {
#pragma unroll
    for (int p = 0; p < ROWS / 64; p++) {
        int idx = tid + p * 256;
        int r = idx >> 2, c = idx & 3;
        uint4 vh = make_uint4(0, 0, 0, 0), vl = make_uint4(0, 0, 0, 0);
        if (r < rows_left) {
            long base = (row0 + r) * (long)K + k0 + c * 8;
            vh = *(const uint4*)&Shi[base];
            vl = *(const uint4*)&Slo[base];
        }
        *(uint4*)&Lh[r * LSTR + c * 8] = vh;
        *(uint4*)&Ll[r * LSTR + c * 8] = vl;
    }
}

// Stage 128 rows x 32 cols of an fp32 matrix, splitting to bf16 hi/lo in
// LDS on the fly (for fp32 A-operands).
__device__ __forceinline__ void stage_f32_split(
    const float* __restrict__ S, long row0, int rows_left, int K, int k0,
    u16* __restrict__ Lh, u16* __restrict__ Ll, int tid) {
#pragma unroll
    for (int p = 0; p < 4; p++) {
        int idx = tid + p * 256;
        int r = idx >> 3, c4 = idx & 7;
        float4 v = make_float4(0.f, 0.f, 0.f, 0.f);
        if (r < rows_left)
            v = *(const float4*)&S[(row0 + r) * (long)K + k0 + c4 * 4];
        u16 h0 = f2b(v.x), h1 = f2b(v.y), h2 = f2b(v.z), h3 = f2b(v.w);
        u16 l0 = f2b(v.x - b2f(h0)), l1 = f2b(v.y - b2f(h1));
        u16 l2 = f2b(v.z - b2f(h2)), l3 = f2b(v.w - b2f(h3));
        uint2 hp, lp;
        hp.x = (u32)h0 | ((u32)h1 << 16); hp.y = (u32)h2 | ((u32)h3 << 16);
        lp.x = (u32)l0 | ((u32)l1 << 16); lp.y = (u32)l2 | ((u32)l3 << 16);
        *(uint2*)&Lh[r * LSTR + c4 * 4] = hp;
        *(uint2*)&Ll[r * LSTR + c4 * 4] = lp;
    }
}

__device__ __forceinline__ void mfma_tile256(
    const u16* __restrict__ Ah, const u16* __restrict__ Al,
    const u16* __restrict__ Bh, const u16* __restrict__ Bl,
    int wm, int wn, int lane, f32x4 acc[4][8]) {
    int lr = lane & 15, kg = lane >> 4;
    s16x8 ah[4], al[4];
#pragma unroll
    for (int fm = 0; fm < 4; fm++) {
        int off = (wm + fm * 16 + lr) * LSTR + kg * 8;
        ah[fm] = *(const s16x8*)&Ah[off];
        al[fm] = *(const s16x8*)&Al[off];
    }
#pragma unroll
    for (int fn = 0; fn < 8; fn++) {
        int off = (wn + fn * 16 + lr) * LSTR + kg * 8;
        s16x8 bh = *(const s16x8*)&Bh[off];
        s16x8 bl = *(const s16x8*)&Bl[off];
#pragma unroll
        for (int fm = 0; fm < 4; fm++) {
            acc[fm][fn] = __builtin_amdgcn_mfma_f32_16x16x32_bf16(
                ah[fm], bh, acc[fm][fn], 0, 0, 0);
            acc[fm][fn] = __builtin_amdgcn_mfma_f32_16x16x32_bf16(
                ah[fm], bl, acc[fm][fn], 0, 0, 0);
            acc[fm][fn] = __builtin_amdgcn_mfma_f32_16x16x32_bf16(
                al[fm], bh, acc[fm][fn], 0, 0, 0);
        }
    }
}

// Merged agg GEMM for both adjacency paths: blocks [0,tA) compute
// aggA = GA @ htA^T (M=N_ALL); blocks [tA,tA+tB) compute aggB = GB @ htB^T
// (M=N_ENTS). Fused BN column stats per path.
__global__ __launch_bounds__(256, 2) void mfma_agg2_kernel(
    const float* __restrict__ GA, const float* __restrict__ GB,
    const u16* __restrict__ AhiB, const u16* __restrict__ AloB,   // htA (gcn2)
    const u16* __restrict__ BhiB, const u16* __restrict__ BloB,   // htB (gcn1)
    float* __restrict__ CA, float* __restrict__ CB,
    float* __restrict__ statsA, float* __restrict__ statsB, int tA) {
    __shared__ u16 Ah[128 * LSTR], Al[128 * LSTR];
    __shared__ u16 Bh[256 * LSTR], Bl[256 * LSTR];
    int tid = threadIdx.x, lane = tid & 63, wid = tid >> 6;
    int wm = (wid >> 1) * 64, wn = (wid & 1) * 128;
    int by = blockIdx.y;
    const float* G; const u16* Hhi; const u16* Hlo;
    float* C; float* stats; int M; long bm0;
    if (by < tA) {
        G = GA; Hhi = AhiB; Hlo = AloB; C = CA; stats = statsA;
        M = N_ALL; bm0 = (long)by * 128;
    } else {
        G = GB; Hhi = BhiB; Hlo = BloB; C = CB; stats = statsB;
        M = N_ENTS; bm0 = (long)(by - tA) * 128;
    }
    int rA = (int)(((long)M - bm0 < 128) ? (long)M - bm0 : 128);
    f32x4 acc[4][8] = {};
    for (int k0 = 0; k0 < 256; k0 += 32) {
        if (k0) __syncthreads();
        stage_f32_split(G, bm0, rA, 256, k0, Ah, Al, tid);
        stage_rows<256>(Hhi, Hlo, 0, 256, 256, k0, Bh, Bl, tid);
        __syncthreads();
        mfma_tile256(Ah, Al, Bh, Bl, wm, wn, lane, acc);
    }
    int lr = lane & 15, lq = lane >> 4;
#pragma unroll
    for (int fm = 0; fm < 4; fm++) {
#pragma unroll
        for (int r = 0; r < 4; r++) {
            long row = bm0 + wm + fm * 16 + lq * 4 + r;
            if (row < M) {
#pragma unroll
                for (int fn = 0; fn < 8; fn++) {
                    long col = wn + fn * 16 + lr;
                    C[row * 256 + col] = acc[fm][fn][r];
                }
            }
        }
    }
    // Fused BN stats (tail rows >= M have zero A-staging -> contribute 0).
#pragma unroll
    for (int fn = 0; fn < 8; fn++) {
        float s = 0.f, sq = 0.f;
#pragma unroll
        for (int fm = 0; fm < 4; fm++)
#pragma unroll
            for (int r = 0; r < 4; r++) {
                float v = acc[fm][fn][r];
                s += v;
                sq += v * v;
            }
        s += __shfl_xor(s, 16);  s += __shfl_xor(s, 32);
        sq += __shfl_xor(sq, 16); sq += __shfl_xor(sq, 32);
        if (lane < 16) {
            int col = wn + fn * 16 + lr;
            atomicAdd(&stats[col], s);
            atomicAdd(&stats[256 + col], sq);
        }
    }
}

// Score GEMM: A=hrn split (512x256), Bt=X split (50000x256), sigmoid out.
// 1D grid of exactly 784 blocks (8 XCDs x 98), XCD-chunked swizzle: the 4
// bm-blocks sharing a B-panel run consecutively on the SAME XCD -> panel
// stays L2-resident (B = 51.7 MB > 32 MB aggregate L2 otherwise).
__global__ __launch_bounds__(256, 2) void mfma_score_kernel(
    const u16* __restrict__ Ahi, const u16* __restrict__ Alo,
    const u16* __restrict__ Bhi, const u16* __restrict__ Blo,
    float* __restrict__ out) {
    __shared__ u16 Ah[128 * LSTR], Al[128 * LSTR];
    __shared__ u16 Bh[256 * LSTR], Bl[256 * LSTR];
    int tid = threadIdx.x, lane = tid & 63, wid = tid >> 6;
    int wm = (wid >> 1) * 64, wn = (wid & 1) * 128;
    int b = blockIdx.x;                 // 784 = 8 * 98 exactly (bijective)
    int w = (b & 7) * 98 + (b >> 3);    // XCD-chunked work index
    long bm0 = (long)(w & 3) * 128;     // bm fastest: 4 blocks/panel adjacent
    long bn0 = (long)(w >> 2) * 256;
    int rB = (int)(((long)N_ENTS - bn0 < 256) ? (long)N_ENTS - bn0 : 256);
    f32x4 acc[4][8] = {};
    for (int k0 = 0; k0 < 256; k0 += 32) {
        if (k0) __syncthreads();
        stage_rows<128>(Ahi, Alo, bm0, 128, 256, k0, Ah, Al, tid);
        stage_rows<256>(Bhi, Blo, bn0, rB, 256, k0, Bh, Bl, tid);
        __syncthreads();
        mfma_tile256(Ah, Al, Bh, Bl, wm, wn, lane, acc);
    }
    int lr = lane & 15, lq = lane >> 4;
#pragma unroll
    for (int fm = 0; fm < 4; fm++) {
#pragma unroll
        for (int r = 0; r < 4; r++) {
            long row = bm0 + wm + fm * 16 + lq * 4 + r;  // < 512 always
#pragma unroll
            for (int fn = 0; fn < 8; fn++) {
                long col = bn0 + wn + fn * 16 + lr;
                if (col < N_ENTS) {
                    float v = acc[fm][fn][r];
                    out[row * N_ENTS + col] = 1.f / (1.f + __expf(-v));
                }
            }
        }
    }
}

// Lin GEMM: Xcat[50000,512] @ H512 with BN+tanh FUSED into the A-loader.
__global__ __launch_bounds__(256, 2) void mfma_lin_kernel(
    const float* __restrict__ Xef, const float* __restrict__ Xrf,
    const float2* __restrict__ coefE, const float2* __restrict__ coefR,
    const u16* __restrict__ Bhi, const u16* __restrict__ Blo,
    u16* __restrict__ Chi, u16* __restrict__ Clo, int M) {
    __shared__ u16 Ah[128 * LSTR], Al[128 * LSTR];
    __shared__ u16 Bh[256 * LSTR], Bl[256 * LSTR];
    int tid = threadIdx.x, lane = tid & 63, wid = tid >> 6;
    int wm = (wid >> 1) * 64, wn = (wid & 1) * 128;
    int bm0 = blockIdx.y * 128;   // gridDim.x == 1 (N=256)
    f32x4 acc[4][8] = {};
    for (int k0 = 0; k0 < 512; k0 += 32) {
        if (k0) __syncthreads();
#pragma unroll
        for (int p = 0; p < 4; p++) {
            int idx = tid + p * 256;
            int r = idx >> 3, c4 = idx & 7;
            int kk = k0 + c4 * 4;          // float4 never crosses a 64-chunk
            int chunk = kk >> 6, s = kk & 63;
            int gm = bm0 + r;
            const float* src = (chunk & 1) ? Xrf : Xef;
            const float2* cf = (chunk & 1) ? coefR : coefE;
            int base = (chunk >> 1) * 64 + s;
            float4 v = make_float4(0.f, 0.f, 0.f, 0.f);
            if (gm < M) v = *(const float4*)&src[(long)gm * 256 + base];
            float2 c0 = cf[base], c1 = cf[base + 1];
            float2 c2 = cf[base + 2], c3 = cf[base + 3];
            v.x = tanhf(fmaf(v.x, c0.x, c0.y));
            v.y = tanhf(fmaf(v.y, c1.x, c1.y));
            v.z = tanhf(fmaf(v.z, c2.x, c2.y));
            v.w = tanhf(fmaf(v.w, c3.x, c3.y));
            u16 h0 = f2b(v.x), h1 = f2b(v.y), h2 = f2b(v.z), h3 = f2b(v.w);
            u16 l0 = f2b(v.x - b2f(h0)), l1 = f2b(v.y - b2f(h1));
            u16 l2 = f2b(v.z - b2f(h2)), l3 = f2b(v.w - b2f(h3));
            uint2 hp, lp;
            hp.x = (u32)h0 | ((u32)h1 << 16); hp.y = (u32)h2 | ((u32)h3 << 16);
            lp.x = (u32)l0 | ((u32)l1 << 16); lp.y = (u32)l2 | ((u32)l3 << 16);
            *(uint2*)&Ah[r * LSTR + c4 * 4] = hp;
            *(uint2*)&Al[r * LSTR + c4 * 4] = lp;
        }
        stage_rows<256>(Bhi, Blo, 0, 256, 512, k0, Bh, Bl, tid);
        __syncthreads();
        mfma_tile256(Ah, Al, Bh, Bl, wm, wn, lane, acc);
    }
    int lr = lane & 15, lq = lane >> 4;
#pragma unroll
    for (int fm = 0; fm < 4; fm++) {
#pragma unroll
        for (int r = 0; r < 4; r++) {
            long row = (long)bm0 + wm + fm * 16 + lq * 4 + r;
            if (row < M) {
#pragma unroll
                for (int fn = 0; fn < 8; fn++) {
                    long col = wn + fn * 16 + lr;
                    float v = acc[fm][fn][r];
                    u16 h = f2b(v);
                    Chi[row * 256 + col] = h;
                    Clo[row * 256 + col] = f2b(v - b2f(h));
                }
            }
        }
    }
}

// ---------------------------------------------------------------------------
// CSR build: histogram, single-block exclusive scan, ticket scatter.
// ---------------------------------------------------------------------------
__global__ __launch_bounds__(256) void hist_kernel(
    const int* __restrict__ rows, int* __restrict__ cnt, int n_edges) {
    int e = blockIdx.x * 256 + threadIdx.x;
    if (e < n_edges) atomicAdd(&cnt[rows[e]], 1);
}

__global__ __launch_bounds__(1024) void exscan_kernel(
    const int* __restrict__ cnt, int n, int* __restrict__ off) {
    __shared__ int part[1024];
    int t = threadIdx.x;
    int chunk = (n + 1023) / 1024;
    int lo = t * chunk;
    int hi = lo + chunk; if (hi > n) hi = n;
    int s = 0;
    for (int i = lo; i < hi; i++) s += cnt[i];
    part[t] = s;
    __syncthreads();
    for (int d = 1; d < 1024; d <<= 1) {
        int v = (t >= d) ? part[t - d] : 0;
        __syncthreads();
        part[t] += v;
        __syncthreads();
    }
    int base = (t == 0) ? 0 : part[t - 1];
    for (int i = lo; i < hi; i++) {
        off[i] = base;
        base += cnt[i];
    }
    if (hi >= n) off[n] = base;
}

__global__ __launch_bounds__(256) void scatter_kernel(
    const int* __restrict__ rows, const int* __restrict__ cols,
    const float* __restrict__ vals, int* __restrict__ cursor,
    int2* __restrict__ pack, int n_edges) {
    int e = blockIdx.x * 256 + threadIdx.x;
    if (e >= n_edges) return;
    int r = rows[e];
    int p = atomicAdd(&cursor[r], 1);
    pack[p] = make_int2(cols[e], __float_as_int(vals[e]));
}

// ---------------------------------------------------------------------------
// MERGED CSR gather for both adjacency paths ((A@X) form). Rows [0,nA) use
// CSR-A -> GA; rows [nA,nA+nB) use CSR-B -> GB. One wave per row; lane owns
// 4 cols; x4 unroll for MLP. Merging fills each gather's straggler tail.
// ---------------------------------------------------------------------------
__global__ __launch_bounds__(256) void csr_gather2_kernel(
    const u16* __restrict__ xhi, const u16* __restrict__ xlo,
    const int* __restrict__ offA, const int2* __restrict__ packA,
    const int* __restrict__ offB, const int2* __restrict__ packB,
    float* __restrict__ GA, float* __restrict__ GB, int nA, int nB) {
    int gid = blockIdx.x * 256 + threadIdx.x;
    int row = gid >> 6;
    int lane = gid & 63;
    const int* off; const int2* pack; float* G; int r;
    if (row < nA) {
        off = offA; pack = packA; G = GA; r = row;
    } else {
        r = row - nA;
        if (r >= nB) return;
        off = offB; pack = packB; G = GB;
    }
    int beg = off[r], end = off[r + 1];
    float4 acc = {0.f, 0.f, 0.f, 0.f};
    int e = beg;
    for (; e + 4 <= end; e += 4) {
        int2 cv0 = pack[e], cv1 = pack[e + 1], cv2 = pack[e + 2], cv3 = pack[e + 3];
        long b0 = (long)cv0.x * 256 + lane * 4;
        long b1 = (long)cv1.x * 256 + lane * 4;
        long b2 = (long)cv2.x * 256 + lane * 4;
        long b3 = (long)cv3.x * 256 + lane * 4;
        uint2 h0 = *(const uint2*)(xhi + b0), l0 = *(const uint2*)(xlo + b0);
        uint2 h1 = *(const uint2*)(xhi + b1), l1 = *(const uint2*)(xlo + b1);
        uint2 h2 = *(const uint2*)(xhi + b2), l2 = *(const uint2*)(xlo + b2);
        uint2 h3 = *(const uint2*)(xhi + b3), l3 = *(const uint2*)(xlo + b3);
        float v0 = __int_as_float(cv0.y), v1 = __int_as_float(cv1.y);
        float v2 = __int_as_float(cv2.y), v3 = __int_as_float(cv3.y);
        acc.x = fmaf(v0, b2f((u16)(h0.x & 0xffff)) + b2f((u16)(l0.x & 0xffff)), acc.x);
        acc.y = fmaf(v0, b2f((u16)(h0.x >> 16))    + b2f((u16)(l0.x >> 16)),    acc.y);
        acc.z = fmaf(v0, b2f((u16)(h0.y & 0xffff)) + b2f((u16)(l0.y & 0xffff)), acc.z);
        acc.w = fmaf(v0, b2f((u16)(h0.y >> 16))    + b2f((u16)(l0.y >> 16)),    acc.w);
        acc.x = fmaf(v1, b2f((u16)(h1.x & 0xffff)) + b2f((u16)(l1.x & 0xffff)), acc.x);
        acc.y = fmaf(v1, b2f((u16)(h1.x >> 16))    + b2f((u16)(l1.x >> 16)),    acc.y);
        acc.z = fmaf(v1, b2f((u16)(h1.y & 0xffff)) + b2f((u16)(l1.y & 0xffff)), acc.z);
        acc.w = fmaf(v1, b2f((u16)(h1.y >> 16))    + b2f((u16)(l1.y >> 16)),    acc.w);
        acc.x = fmaf(v2, b2f((u16)(h2.x & 0xffff)) + b2f((u16)(l2.x & 0xffff)), acc.x);
        acc.y = fmaf(v2, b2f((u16)(h2.x >> 16))    + b2f((u16)(l2.x >> 16)),    acc.y);
        acc.z = fmaf(v2, b2f((u16)(h2.y & 0xffff)) + b2f((u16)(l2.y & 0xffff)), acc.z);
        acc.w = fmaf(v2, b2f((u16)(h2.y >> 16))    + b2f((u16)(l2.y >> 16)),    acc.w);
        acc.x = fmaf(v3, b2f((u16)(h3.x & 0xffff)) + b2f((u16)(l3.x & 0xffff)), acc.x);
        acc.y = fmaf(v3, b2f((u16)(h3.x >> 16))    + b2f((u16)(l3.x >> 16)),    acc.y);
        acc.z = fmaf(v3, b2f((u16)(h3.y & 0xffff)) + b2f((u16)(l3.y & 0xffff)), acc.z);
        acc.w = fmaf(v3, b2f((u16)(h3.y >> 16))    + b2f((u16)(l3.y >> 16)),    acc.w);
    }
    for (; e < end; e++) {
        int2 cv = pack[e];
        float v = __int_as_float(cv.y);
        long b = (long)cv.x * 256 + lane * 4;
        uint2 hv = *(const uint2*)(xhi + b), lv = *(const uint2*)(xlo + b);
        acc.x = fmaf(v, b2f((u16)(hv.x & 0xffff)) + b2f((u16)(lv.x & 0xffff)), acc.x);
        acc.y = fmaf(v, b2f((u16)(hv.x >> 16))    + b2f((u16)(lv.x >> 16)),    acc.y);
        acc.z = fmaf(v, b2f((u16)(hv.y & 0xffff)) + b2f((u16)(lv.y & 0xffff)), acc.z);
        acc.w = fmaf(v, b2f((u16)(hv.y >> 16))    + b2f((u16)(lv.y >> 16)),    acc.w);
    }
    *(float4*)(G + (long)r * 256 + lane * 4) = acc;
}

// ---------------------------------------------------------------------------
// BN stats (hr path only) + BN apply-split (hr) + rels-tail BN+tanh+split
// ---------------------------------------------------------------------------
__global__ __launch_bounds__(256) void bn_stats_kernel(
    const float* __restrict__ x, int n, float* __restrict__ stats) {
    int col = threadIdx.x;
    int r0 = blockIdx.x * 256;
    int r1 = r0 + 256;
    if (r1 > n) r1 = n;
    float s = 0.f, sq = 0.f;
    for (int r = r0; r < r1; r++) {
        float v = x[(long)r * 256 + col];
        s += v;
        sq += v * v;
    }
    atomicAdd(&stats[col], s);
    atomicAdd(&stats[256 + col], sq);
}

// BN apply writing bf16 hi/lo split directly (hr path; no tanh).
__global__ __launch_bounds__(256) void bn_apply_split_kernel(
    const float* __restrict__ x, u16* __restrict__ hi, u16* __restrict__ lo,
    int n, const float* __restrict__ gamma, const float* __restrict__ beta,
    const float* __restrict__ stats) {
    long total = (long)n * 256;
    float inv_n = 1.f / (float)n;
    long idx = (long)blockIdx.x * 256 + threadIdx.x;
    if (idx >= total) return;
    int col = (int)(idx & 255);
    float mean = stats[col] * inv_n;
    float var = stats[256 + col] * inv_n - mean * mean;
    float sc = rsqrtf(var + BN_EPS) * gamma[col];
    float v = (x[idx] - mean) * sc + beta[col];
    u16 h = f2b(v);
    hi[idx] = h;
    lo[idx] = f2b(v - b2f(h));
}

// Rels tail: BN+tanh from coef, then split to xr bf16 buffers.
__global__ __launch_bounds__(256) void bn_tanh_split_kernel(
    const float* __restrict__ x, const float2* __restrict__ coef,
    u16* __restrict__ hi, u16* __restrict__ lo, long total) {
    long idx = (long)blockIdx.x * 256 + threadIdx.x;
    if (idx >= total) return;
    int col = (int)(idx & 255);
    float2 c = coef[col];
    float v = tanhf(fmaf(x[idx], c.x, c.y));
    u16 h = f2b(v);
    hi[idx] = h;
    lo[idx] = f2b(v - b2f(h));
}

// ---------------------------------------------------------------------------
// Quaternion vec-vec multiplication (reads xr split, err ~2^-17).
// ---------------------------------------------------------------------------
__global__ __launch_bounds__(256) void hr_kernel(
    const u16* __restrict__ xhi, const u16* __restrict__ xlo,
    const int* __restrict__ e1_idx, const int* __restrict__ r_idx,
    float* __restrict__ hr) {
    int idx = blockIdx.x * 256 + threadIdx.x;
    if (idx >= BATCH * 64) return;
    int b = idx >> 6, s = idx & 63;
    long hrow = (long)e1_idx[b] * 256;
    long prow = ((long)N_ENTS + r_idx[b]) * 256;
    float qr = b2f(xhi[hrow + s])       + b2f(xlo[hrow + s]);
    float qi = b2f(xhi[hrow + 64 + s])  + b2f(xlo[hrow + 64 + s]);
    float qj = b2f(xhi[hrow + 128 + s]) + b2f(xlo[hrow + 128 + s]);
    float qk = b2f(xhi[hrow + 192 + s]) + b2f(xlo[hrow + 192 + s]);
    float pr = b2f(xhi[prow + s])       + b2f(xlo[prow + s]);
    float pi = b2f(xhi[prow + 64 + s])  + b2f(xlo[prow + 64 + s]);
    float pj = b2f(xhi[prow + 128 + s]) + b2f(xlo[prow + 128 + s]);
    float pk = b2f(xhi[prow + 192 + s]) + b2f(xlo[prow + 192 + s]);
    float inv = rsqrtf(pr * pr + pi * pi + pj * pj + pk * pk);
    pr *= inv; pi *= inv; pj *= inv; pk *= inv;
    float* o = hr + (long)b * 256 + s;
    o[0]   = qr * pr - qi * pi - qj * pj - qk * pk;
    o[64]  = qi * pr + qr * pi - qk * pj + qj * pk;
    o[128] = qj * pr + qk * pi + qr * pj - qi * pk;
    o[192] = qk * pr - qj * pi + qi * pj + qr * pk;
}

// ---------------------------------------------------------------------------
// Host-side orchestration
// ---------------------------------------------------------------------------
struct Csr {
    int* off;
    int* cur;
    int2* pack;
};

struct Ws {
    float* GA;          // (50500,256) gather result, adjr path
    float* GB;          // (50000,256) gather result, adj path
    float* aggA;        // (50500,256) raw gcn2 output (pre-BN)
    float* aggB;        // (50000,256) raw gcn1 output (pre-BN)
    float* hr;          // (512,256)
    float* statsHr;     // 512
    float* statsA;      // 512
    float* statsB;      // 512
    float2* coefA;      // 256
    float2* coefB;      // 256
    u16* xr_hi;         // (50500,256) bf16 split of current XR
    u16* xr_lo;
    u16* hrn_hi;        // (512,256)
    u16* hrn_lo;
    u16* ht_hi;         // (256,512) max — gcn2 agg HT, then lin HT
    u16* ht_lo;
    u16* ht1_hi;        // (256,256) — gcn1 agg HT
    u16* ht1_lo;
    Csr adj;
    Csr adjr;
};

static void build_csr(const int* rows, const int* cols, const float* vals,
                      int n_rows, const Csr& c, hipStream_t stream) {
    hipMemsetAsync(c.cur, 0, (size_t)n_rows * sizeof(int), stream);
    hist_kernel<<<(NEDGE + 255) / 256, 256, 0, stream>>>(rows, c.cur, NEDGE);
    exscan_kernel<<<1, 1024, 0, stream>>>(c.cur, n_rows, c.off);
    hipMemcpyAsync(c.cur, c.off, (size_t)n_rows * sizeof(int),
                   hipMemcpyDeviceToDevice, stream);
    scatter_kernel<<<(NEDGE + 255) / 256, 256, 0, stream>>>(
        rows, cols, vals, c.cur, c.pack, NEDGE);
}

static void run_split(const float* x, u16* hi, u16* lo, long n,
                      hipStream_t stream) {
    long n4 = n / 4;
    split_kernel<<<(int)((n4 + 255) / 256), 256, 0, stream>>>(x, hi, lo, n4);
}

static void run_score(const int* e1_idx, const int* r_idx, const float* gamma,
                      const float* beta, float* out_l, const Ws& w,
                      hipStream_t stream) {
    hr_kernel<<<(BATCH * 64) / 256, 256, 0, stream>>>(
        w.xr_hi, w.xr_lo, e1_idx, r_idx, w.hr);
    hipMemsetAsync(w.statsHr, 0, 512 * sizeof(float), stream);
    bn_stats_kernel<<<(BATCH + 255) / 256, 256, 0, stream>>>(w.hr, BATCH, w.statsHr);
    bn_apply_split_kernel<<<(BATCH * 256) / 256, 256, 0, stream>>>(
        w.hr, w.hrn_hi, w.hrn_lo, BATCH, gamma, beta, w.statsHr);
    // 784 = (50176/256 bn-tiles = 196) x (512/128 bm-tiles = 4); 784 % 8 == 0.
    mfma_score_kernel<<<784, 256, 0, stream>>>(
        w.hrn_hi, w.hrn_lo, w.xr_hi, w.xr_lo, out_l);
}

extern "C" void kernel_launch(void* const* d_in, const int* in_sizes, int n_in,
                              void* d_out, int out_size, void* d_ws, size_t ws_size,
                              hipStream_t stream) {
    const int*   e1_idx     = (const int*)d_in[0];
    const int*   r_idx      = (const int*)d_in[1];
    const float* emb        = (const float*)d_in[2];
    const float* gcn1_w     = (const float*)d_in[3];
    const float* gcn2_w     = (const float*)d_in[4];
    const float* gcn1_gamma = (const float*)d_in[5];
    const float* gcn1_beta  = (const float*)d_in[6];
    const float* gcn2_gamma = (const float*)d_in[7];
    const float* gcn2_beta  = (const float*)d_in[8];
    const float* lin_ents   = (const float*)d_in[9];
    const float* bn_s_gamma = (const float*)d_in[10];
    const float* bn_s_beta  = (const float*)d_in[11];
    const int*   adj_rows   = (const int*)d_in[12];
    const int*   adj_cols   = (const int*)d_in[13];
    const float* adj_vals   = (const float*)d_in[14];
    const int*   adjr_rows  = (const int*)d_in[15];
    const int*   adjr_cols  = (const int*)d_in[16];
    const float* adjr_vals  = (const float*)d_in[17];
    float* out = (float*)d_out;

    Ws w;
    float* f = (float*)d_ws;
    w.GA         = f; f += (long)N_ALL * EMB;
    w.GB         = f; f += (long)N_ENTS * EMB;
    w.aggA       = f; f += (long)N_ALL * EMB;
    w.aggB       = f; f += (long)N_ENTS * EMB;
    w.hr         = f; f += BATCH * EMB;
    w.statsHr    = f; f += 512;
    w.statsA     = f; f += 512;
    w.statsB     = f; f += 512;
    w.coefA      = (float2*)f; f += 512;
    w.coefB      = (float2*)f; f += 512;
    w.xr_hi  = (u16*)f; f += (long)N_ALL * EMB / 2;
    w.xr_lo  = (u16*)f; f += (long)N_ALL * EMB / 2;
    w.hrn_hi = (u16*)f; f += BATCH * EMB / 2;
    w.hrn_lo = (u16*)f; f += BATCH * EMB / 2;
    w.ht_hi  = (u16*)f; f += 256 * 512 / 2;
    w.ht_lo  = (u16*)f; f += 256 * 512 / 2;
    w.ht1_hi = (u16*)f; f += 256 * 256 / 2;
    w.ht1_lo = (u16*)f; f += 256 * 256 / 2;
    int* ip = (int*)f;
    w.adj.pack  = (int2*)ip; ip += 2 * NEDGE;
    w.adjr.pack = (int2*)ip; ip += 2 * NEDGE;
    w.adj.off    = ip; ip += N_ENTS + 1;
    w.adj.cur    = ip; ip += N_ENTS;
    w.adjr.off   = ip; ip += N_ALL + 1;
    w.adjr.cur   = ip; ip += N_ALL;

    // Build both CSRs once; reused by both layers.
    build_csr(adj_rows, adj_cols, adj_vals, N_ENTS, w.adj, stream);
    build_csr(adjr_rows, adjr_cols, adjr_vals, N_ALL, w.adjr, stream);

    // Split embeddings (entities+rels) once into the shared xr buffers.
    run_split(emb, w.xr_hi, w.xr_lo, (long)N_ALL * EMB, stream);

    // score 0
    run_score(e1_idx, r_idx, bn_s_gamma, bn_s_beta, out, w, stream);

    const int tA = (N_ALL + 127) / 128;    // 395
    const int tB = (N_ENTS + 127) / 128;   // 391

    for (int l = 0; l < 2; l++) {
        hipMemsetAsync(w.statsA, 0, 512 * sizeof(float), stream);
        hipMemsetAsync(w.statsB, 0, 512 * sizeof(float), stream);
        build_ht_kernel<<<(256 * 256) / 256, 256, 0, stream>>>(
            gcn2_w + (long)l * 64 * 256, w.ht_hi, w.ht_lo, 64);
        build_ht_kernel<<<(256 * 256) / 256, 256, 0, stream>>>(
            gcn1_w + (long)l * 64 * 256, w.ht1_hi, w.ht1_lo, 64);
        // Merged gather for both paths (fills straggler tails).
        int grows = N_ALL + N_ENTS;
        csr_gather2_kernel<<<(grows * 64 + 255) / 256, 256, 0, stream>>>(
            w.xr_hi, w.xr_lo, w.adjr.off, w.adjr.pack, w.adj.off, w.adj.pack,
            w.GA, w.GB, N_ALL, N_ENTS);
        // Merged agg GEMM (+fused BN stats per path).
        dim3 g2(1, tA + tB);
        mfma_agg2_kernel<<<g2, 256, 0, stream>>>(
            w.GA, w.GB, w.ht_hi, w.ht_lo, w.ht1_hi, w.ht1_lo,
            w.aggA, w.aggB, w.statsA, w.statsB, tA);
        bn_coeff_kernel<<<1, 256, 0, stream>>>(
            w.statsA, N_ALL, gcn2_gamma + l * 256, gcn2_beta + l * 256, w.coefA);
        bn_coeff_kernel<<<1, 256, 0, stream>>>(
            w.statsB, N_ENTS, gcn1_gamma + l * 256, gcn1_beta + l * 256, w.coefB);
        build_ht_kernel<<<(256 * 512) / 256, 256, 0, stream>>>(
            lin_ents + (long)l * 128 * 256, w.ht_hi, w.ht_lo, 128);
        dim3 g(1, (N_ENTS + 127) / 128);
        mfma_lin_kernel<<<g, 256, 0, stream>>>(
            w.aggB, w.aggA, w.coefB, w.coefA, w.ht_hi, w.ht_lo,
            w.xr_hi, w.xr_lo, N_ENTS);
        // Rels tail: BN+tanh (gcn2 coef) + split into xr directly.
        bn_tanh_split_kernel<<<(N_RELS * EMB + 255) / 256, 256, 0, stream>>>(
            w.aggA + (long)N_ENTS * EMB, w.coefA,
            w.xr_hi + (long)N_ENTS * EMB, w.xr_lo + (long)N_ENTS * EMB,
            (long)N_RELS * EMB);
        run_score(e1_idx, r_idx, bn_s_gamma + (l + 1) * 256,
                  bn_s_beta + (l + 1) * 256,
                  out + (long)(l + 1) * BATCH * N_ENTS, w, stream);
    }
}